// Round 1
// baseline (3923.902 us; speedup 1.0000x reference)
//
#include <hip/hip_runtime.h>
#include <hip/hip_bf16.h>

#define NEG_SLOPE 0.2f

// ---------- ordered-uint encoding for float atomicMax ----------
__device__ __forceinline__ unsigned enc_f32(float f) {
    unsigned b = __float_as_uint(f);
    return (b & 0x80000000u) ? ~b : (b | 0x80000000u);
}
__device__ __forceinline__ float dec_f32(unsigned u) {
    unsigned b = (u & 0x80000000u) ? (u & 0x7FFFFFFFu) : ~u;
    return __uint_as_float(b);
}

// ---------- init: zero block + (-inf) max block ----------
__global__ __launch_bounds__(256) void init_kernel(float* zbase, size_t nz,
                                                   unsigned* mbase, size_t nm) {
    size_t i = (size_t)blockIdx.x * 256 + threadIdx.x;
    size_t stride = (size_t)gridDim.x * 256;
    for (size_t k = i; k < nz; k += stride) zbase[k] = 0.f;
    for (size_t k = i; k < nm; k += stride) mbase[k] = 0x007FFFFFu;  // enc(-inf)
}

// ---------- tiled fp32 GEMM: C[M,N] = A[M,K] @ B[K,N] ----------
#define KC 32
__global__ __launch_bounds__(256) void gemm_tile(const float* __restrict__ A,
                                                 const float* __restrict__ B,
                                                 float* __restrict__ C,
                                                 int M, int N, int K) {
    __shared__ float As[KC][64 + 1];
    __shared__ float Bs[KC][64 + 1];
    int row0 = blockIdx.x * 64;
    int col0 = blockIdx.y * 64;
    int tid = threadIdx.x;
    int tx = tid & 15, ty = tid >> 4;
    float acc[4][4] = {};
    for (int kc = 0; kc < K; kc += KC) {
        #pragma unroll
        for (int i = 0; i < 8; i++) {
            int idx = tid + i * 256;           // 64x32 A tile
            int m = idx >> 5, k = idx & 31;
            int r = row0 + m;
            As[k][m] = (r < M) ? A[(size_t)r * K + kc + k] : 0.f;
        }
        #pragma unroll
        for (int i = 0; i < 8; i++) {
            int idx = tid + i * 256;           // 32x64 B tile
            int k = idx >> 6, c = idx & 63;
            Bs[k][c] = B[(size_t)(kc + k) * N + col0 + c];
        }
        __syncthreads();
        #pragma unroll
        for (int kk = 0; kk < KC; kk++) {
            float a[4], b[4];
            #pragma unroll
            for (int i = 0; i < 4; i++) a[i] = As[kk][ty * 4 + i];
            #pragma unroll
            for (int j = 0; j < 4; j++) b[j] = Bs[kk][tx * 4 + j];
            #pragma unroll
            for (int i = 0; i < 4; i++)
                #pragma unroll
                for (int j = 0; j < 4; j++) acc[i][j] += a[i] * b[j];
        }
        __syncthreads();
    }
    #pragma unroll
    for (int i = 0; i < 4; i++) {
        int r = row0 + ty * 4 + i;
        if (r < M) {
            #pragma unroll
            for (int j = 0; j < 4; j++)
                C[(size_t)r * N + col0 + tx * 4 + j] = acc[i][j];
        }
    }
}

// ---------- el/er layer1: feat [N,256] (4 heads x 64), wave per node ----------
__global__ __launch_bounds__(256) void elr1_kernel(const float* __restrict__ feat,
                                                   const float* __restrict__ al,
                                                   const float* __restrict__ ar,
                                                   float* __restrict__ el,
                                                   float* __restrict__ er, int N) {
    int wave = (blockIdx.x * 256 + threadIdx.x) >> 6;
    int lane = threadIdx.x & 63;
    if (wave >= N) return;
    const float4 f = *(const float4*)(feat + (size_t)wave * 256 + lane * 4);
    int h = lane >> 4;
    int d0 = (lane & 15) * 4;
    const float4 a = *(const float4*)(al + h * 64 + d0);
    const float4 b = *(const float4*)(ar + h * 64 + d0);
    float dl = f.x * a.x + f.y * a.y + f.z * a.z + f.w * a.w;
    float dr = f.x * b.x + f.y * b.y + f.z * b.z + f.w * b.w;
    #pragma unroll
    for (int off = 1; off < 16; off <<= 1) {
        dl += __shfl_xor(dl, off);
        dr += __shfl_xor(dr, off);
    }
    if ((lane & 15) == 0) {
        el[wave * 4 + h] = dl;
        er[wave * 4 + h] = dr;
    }
}

// ---------- el/er layer2: feat [N,64], wave per node ----------
__global__ __launch_bounds__(256) void elr2_kernel(const float* __restrict__ feat,
                                                   const float* __restrict__ al,
                                                   const float* __restrict__ ar,
                                                   float* __restrict__ el,
                                                   float* __restrict__ er, int N) {
    int wave = (blockIdx.x * 256 + threadIdx.x) >> 6;
    int lane = threadIdx.x & 63;
    if (wave >= N) return;
    float f = feat[(size_t)wave * 64 + lane];
    float dl = f * al[lane], dr = f * ar[lane];
    #pragma unroll
    for (int off = 1; off < 64; off <<= 1) {
        dl += __shfl_xor(dl, off);
        dr += __shfl_xor(dr, off);
    }
    if (lane == 0) { el[wave] = dl; er[wave] = dr; }
}

// ---------- layer1 scores: per edge, 4 heads ----------
__global__ __launch_bounds__(256) void score1_kernel(const int* __restrict__ src,
                                                     const int* __restrict__ dst,
                                                     const float* __restrict__ el,
                                                     const float* __restrict__ er,
                                                     float* __restrict__ sc,
                                                     unsigned* __restrict__ mmax, int E) {
    int e = blockIdx.x * 256 + threadIdx.x;
    if (e >= E) return;
    int s = src[e], d = dst[e];
    float4 l = *(const float4*)(el + (size_t)s * 4);
    float4 r = *(const float4*)(er + (size_t)d * 4);
    float4 v;
    v.x = l.x + r.x; v.x = v.x > 0.f ? v.x : NEG_SLOPE * v.x;
    v.y = l.y + r.y; v.y = v.y > 0.f ? v.y : NEG_SLOPE * v.y;
    v.z = l.z + r.z; v.z = v.z > 0.f ? v.z : NEG_SLOPE * v.z;
    v.w = l.w + r.w; v.w = v.w > 0.f ? v.w : NEG_SLOPE * v.w;
    *(float4*)(sc + (size_t)e * 4) = v;
    atomicMax(mmax + (size_t)d * 4 + 0, enc_f32(v.x));
    atomicMax(mmax + (size_t)d * 4 + 1, enc_f32(v.y));
    atomicMax(mmax + (size_t)d * 4 + 2, enc_f32(v.z));
    atomicMax(mmax + (size_t)d * 4 + 3, enc_f32(v.w));
}

__global__ __launch_bounds__(256) void expden1_kernel(const int* __restrict__ dst,
                                                      float* __restrict__ sc,
                                                      const unsigned* __restrict__ mmax,
                                                      float* __restrict__ den, int E) {
    int e = blockIdx.x * 256 + threadIdx.x;
    if (e >= E) return;
    int d = dst[e];
    float4 v = *(float4*)(sc + (size_t)e * 4);
    uint4 mu = *(const uint4*)(mmax + (size_t)d * 4);
    v.x = __expf(v.x - dec_f32(mu.x));
    v.y = __expf(v.y - dec_f32(mu.y));
    v.z = __expf(v.z - dec_f32(mu.z));
    v.w = __expf(v.w - dec_f32(mu.w));
    *(float4*)(sc + (size_t)e * 4) = v;
    atomicAdd(den + (size_t)d * 4 + 0, v.x);
    atomicAdd(den + (size_t)d * 4 + 1, v.y);
    atomicAdd(den + (size_t)d * 4 + 2, v.z);
    atomicAdd(den + (size_t)d * 4 + 3, v.w);
}

// ---------- layer1 messages: thread per (edge, 4 dims); 64 threads/edge ----------
__global__ __launch_bounds__(256) void msg1_kernel(const int* __restrict__ src,
                                                   const int* __restrict__ dst,
                                                   const float* __restrict__ feat,
                                                   const float* __restrict__ a,
                                                   const float* __restrict__ den,
                                                   float* __restrict__ out, int E) {
    long long gid = (long long)blockIdx.x * 256 + threadIdx.x;
    long long tot = (long long)E * 64;
    if (gid >= tot) return;
    int e = (int)(gid >> 6);
    int t = (int)(gid & 63);
    int h = t >> 4;
    int off = h * 64 + (t & 15) * 4;
    int s = src[e], d = dst[e];
    float w = a[(size_t)e * 4 + h] / den[(size_t)d * 4 + h];
    float4 f = *(const float4*)(feat + (size_t)s * 256 + off);
    float* o = out + (size_t)d * 256 + off;
    atomicAdd(o + 0, f.x * w);
    atomicAdd(o + 1, f.y * w);
    atomicAdd(o + 2, f.z * w);
    atomicAdd(o + 3, f.w * w);
}

// ---------- bias + relu (in place), layer1 out [N,256] ----------
__global__ __launch_bounds__(256) void bias_relu1(float* __restrict__ out,
                                                  const float* __restrict__ bias, int N) {
    int gid = blockIdx.x * 256 + threadIdx.x;  // over N*64 float4s
    if (gid >= N * 64) return;
    int c4 = gid & 63;
    float4 v = *(float4*)(out + (size_t)gid * 4);
    float4 b = *(const float4*)(bias + c4 * 4);
    v.x = fmaxf(v.x + b.x, 0.f);
    v.y = fmaxf(v.y + b.y, 0.f);
    v.z = fmaxf(v.z + b.z, 0.f);
    v.w = fmaxf(v.w + b.w, 0.f);
    *(float4*)(out + (size_t)gid * 4) = v;
}

// ---------- layer2 scores (1 head) ----------
__global__ __launch_bounds__(256) void score2_kernel(const int* __restrict__ src,
                                                     const int* __restrict__ dst,
                                                     const float* __restrict__ el,
                                                     const float* __restrict__ er,
                                                     float* __restrict__ sc,
                                                     unsigned* __restrict__ mmax, int E) {
    int e = blockIdx.x * 256 + threadIdx.x;
    if (e >= E) return;
    float v = el[src[e]] + er[dst[e]];
    v = v > 0.f ? v : NEG_SLOPE * v;
    sc[e] = v;
    atomicMax(mmax + dst[e], enc_f32(v));
}

__global__ __launch_bounds__(256) void expden2_kernel(const int* __restrict__ dst,
                                                      float* __restrict__ sc,
                                                      const unsigned* __restrict__ mmax,
                                                      float* __restrict__ den, int E) {
    int e = blockIdx.x * 256 + threadIdx.x;
    if (e >= E) return;
    int d = dst[e];
    float v = __expf(sc[e] - dec_f32(mmax[d]));
    sc[e] = v;
    atomicAdd(den + d, v);
}

// ---------- layer2 messages: thread per (edge, 4 dims); 16 threads/edge ----------
__global__ __launch_bounds__(256) void msg2_kernel(const int* __restrict__ src,
                                                   const int* __restrict__ dst,
                                                   const float* __restrict__ feat,
                                                   const float* __restrict__ a,
                                                   const float* __restrict__ den,
                                                   float* __restrict__ out, int E) {
    long long gid = (long long)blockIdx.x * 256 + threadIdx.x;
    long long tot = (long long)E * 16;
    if (gid >= tot) return;
    int e = (int)(gid >> 4);
    int off = (int)(gid & 15) * 4;
    int s = src[e], d = dst[e];
    float w = a[e] / den[d];
    float4 f = *(const float4*)(feat + (size_t)s * 64 + off);
    float* o = out + (size_t)d * 64 + off;
    atomicAdd(o + 0, f.x * w);
    atomicAdd(o + 1, f.y * w);
    atomicAdd(o + 2, f.z * w);
    atomicAdd(o + 3, f.w * w);
}

// ---------- final: bias+relu, write graph_output and per-node sum ----------
__global__ __launch_bounds__(256) void final_kernel(const float* __restrict__ out2,
                                                    const float* __restrict__ bias,
                                                    float* __restrict__ emb,
                                                    float* __restrict__ go, int N) {
    int wave = (blockIdx.x * 256 + threadIdx.x) >> 6;
    int lane = threadIdx.x & 63;
    if (wave >= N) return;
    float v = out2[(size_t)wave * 64 + lane] + bias[lane];
    v = fmaxf(v, 0.f);
    go[(size_t)wave * 64 + lane] = v;
    float s = v;
    #pragma unroll
    for (int off = 1; off < 64; off <<= 1) s += __shfl_xor(s, off);
    if (lane == 0) emb[wave] = s;
}

extern "C" void kernel_launch(void* const* d_in, const int* in_sizes, int n_in,
                              void* d_out, int out_size, void* d_ws, size_t ws_size,
                              hipStream_t stream) {
    const float* x   = (const float*)d_in[0];
    const int*   src = (const int*)d_in[1];
    const int*   dst = (const int*)d_in[2];
    const float* W1  = (const float*)d_in[3];
    const float* al1 = (const float*)d_in[4];
    const float* ar1 = (const float*)d_in[5];
    const float* b1  = (const float*)d_in[6];
    const float* W2  = (const float*)d_in[7];
    const float* al2 = (const float*)d_in[8];
    const float* ar2 = (const float*)d_in[9];
    const float* b2  = (const float*)d_in[10];
    const int N = in_sizes[0] / 128;
    const int E = in_sizes[1];

    float* ws = (float*)d_ws;
    size_t off = 0;
    auto alloc = [&](size_t n) { size_t o = off; off += (n + 63) & ~(size_t)63; return o; };
    size_t feat1 = alloc((size_t)N * 256);
    size_t zero0 = off;
    size_t out1  = alloc((size_t)N * 256);
    size_t den1  = alloc((size_t)N * 4);
    size_t out2  = alloc((size_t)N * 64);
    size_t den2  = alloc((size_t)N);
    size_t zn    = off - zero0;
    size_t mb0   = off;
    size_t m1    = alloc((size_t)N * 4);
    size_t m2    = alloc((size_t)N);
    size_t mn    = off - mb0;
    size_t el1   = alloc((size_t)N * 4);
    size_t er1   = alloc((size_t)N * 4);
    size_t a1    = alloc((size_t)E * 4);
    size_t feat2 = alloc((size_t)N * 64);
    size_t el2   = alloc((size_t)N);
    size_t er2   = alloc((size_t)N);
    size_t a2    = alloc((size_t)E);
    (void)ws_size;

    init_kernel<<<2048, 256, 0, stream>>>(ws + zero0, zn, (unsigned*)(ws + mb0), mn);

    dim3 g1((N + 63) / 64, 4);
    gemm_tile<<<g1, 256, 0, stream>>>(x, W1, ws + feat1, N, 256, 128);

    elr1_kernel<<<(N + 3) / 4, 256, 0, stream>>>(ws + feat1, al1, ar1, ws + el1, ws + er1, N);

    score1_kernel<<<(E + 255) / 256, 256, 0, stream>>>(src, dst, ws + el1, ws + er1,
                                                       ws + a1, (unsigned*)(ws + m1), E);
    expden1_kernel<<<(E + 255) / 256, 256, 0, stream>>>(dst, ws + a1,
                                                        (unsigned*)(ws + m1), ws + den1, E);
    {
        long long tot = (long long)E * 64;
        msg1_kernel<<<(unsigned)((tot + 255) / 256), 256, 0, stream>>>(
            src, dst, ws + feat1, ws + a1, ws + den1, ws + out1, E);
    }
    bias_relu1<<<(N * 64 + 255) / 256, 256, 0, stream>>>(ws + out1, b1, N);

    dim3 g2((N + 63) / 64, 1);
    gemm_tile<<<g2, 256, 0, stream>>>(ws + out1, W2, ws + feat2, N, 64, 256);

    elr2_kernel<<<(N + 3) / 4, 256, 0, stream>>>(ws + feat2, al2, ar2, ws + el2, ws + er2, N);

    score2_kernel<<<(E + 255) / 256, 256, 0, stream>>>(src, dst, ws + el2, ws + er2,
                                                       ws + a2, (unsigned*)(ws + m2), E);
    expden2_kernel<<<(E + 255) / 256, 256, 0, stream>>>(dst, ws + a2,
                                                        (unsigned*)(ws + m2), ws + den2, E);
    {
        long long tot = (long long)E * 16;
        msg2_kernel<<<(unsigned)((tot + 255) / 256), 256, 0, stream>>>(
            src, dst, ws + feat2, ws + a2, ws + den2, ws + out2, E);
    }
    final_kernel<<<(N + 3) / 4, 256, 0, stream>>>(ws + out2, b2, (float*)d_out,
                                                  (float*)d_out + N, N);
}

// Round 2
// 541.109 us; speedup vs baseline: 7.2516x; 7.2516x over previous
//
#include <hip/hip_runtime.h>
#include <hip/hip_bf16.h>

#define NEG_SLOPE 0.2f

// ---------- zero ints ----------
__global__ __launch_bounds__(256) void zero_kernel(int* p, int n) {
    int i = blockIdx.x * 256 + threadIdx.x;
    int stride = gridDim.x * 256;
    for (int k = i; k < n; k += stride) p[k] = 0;
}

// ---------- CSR build: histogram ----------
__global__ __launch_bounds__(256) void hist_kernel(const int* __restrict__ dst,
                                                   int* __restrict__ counts, int E) {
    int e = blockIdx.x * 256 + threadIdx.x;
    if (e < E) atomicAdd(counts + dst[e], 1);
}

// ---------- CSR build: per-block sums ----------
__global__ __launch_bounds__(256) void bsum_kernel(const int* __restrict__ counts,
                                                   int* __restrict__ bsum, int N) {
    __shared__ int sh[256];
    int i = blockIdx.x * 256 + threadIdx.x;
    int v = (i < N) ? counts[i] : 0;
    sh[threadIdx.x] = v;
    __syncthreads();
    for (int off = 128; off > 0; off >>= 1) {
        if (threadIdx.x < off) sh[threadIdx.x] += sh[threadIdx.x + off];
        __syncthreads();
    }
    if (threadIdx.x == 0) bsum[blockIdx.x] = sh[0];
}

// ---------- CSR build: scan block sums (single block, nb<=256 per chunk) ----------
__global__ __launch_bounds__(256) void bscan_kernel(int* __restrict__ bsum, int nb,
                                                    int* __restrict__ rowptr, int N, int E) {
    __shared__ int sh[256];
    int tid = threadIdx.x;
    int carry = 0;
    for (int base = 0; base < nb; base += 256) {
        int i = base + tid;
        int v = (i < nb) ? bsum[i] : 0;
        sh[tid] = v;
        __syncthreads();
        for (int off = 1; off < 256; off <<= 1) {
            int t = (tid >= off) ? sh[tid - off] : 0;
            __syncthreads();
            sh[tid] += t;
            __syncthreads();
        }
        if (i < nb) bsum[i] = carry + sh[tid] - v;  // exclusive
        int tot = sh[255];
        __syncthreads();
        carry += tot;
    }
    if (tid == 0) rowptr[N] = E;
}

// ---------- CSR build: per-block scan + offset -> rowptr ----------
__global__ __launch_bounds__(256) void rowptr_kernel(const int* __restrict__ counts,
                                                     const int* __restrict__ bsum,
                                                     int* __restrict__ rowptr, int N) {
    __shared__ int sh[256];
    int i = blockIdx.x * 256 + threadIdx.x;
    int tid = threadIdx.x;
    int v = (i < N) ? counts[i] : 0;
    sh[tid] = v;
    __syncthreads();
    for (int off = 1; off < 256; off <<= 1) {
        int t = (tid >= off) ? sh[tid - off] : 0;
        __syncthreads();
        sh[tid] += t;
        __syncthreads();
    }
    if (i < N) rowptr[i] = bsum[blockIdx.x] + sh[tid] - v;  // exclusive
}

// ---------- CSR build: fill sources ----------
__global__ __launch_bounds__(256) void fill_kernel(const int* __restrict__ src,
                                                   const int* __restrict__ dst,
                                                   const int* __restrict__ rowptr,
                                                   int* __restrict__ cursor,
                                                   int* __restrict__ csr_src, int E) {
    int e = blockIdx.x * 256 + threadIdx.x;
    if (e >= E) return;
    int d = dst[e];
    int pos = atomicAdd(cursor + d, 1);
    csr_src[rowptr[d] + pos] = src[e];
}

// ---------- tiled fp32 GEMM: C[M,N] = A[M,K] @ B[K,N] ----------
#define KC 32
__global__ __launch_bounds__(256) void gemm_tile(const float* __restrict__ A,
                                                 const float* __restrict__ B,
                                                 float* __restrict__ C,
                                                 int M, int N, int K) {
    __shared__ float As[KC][64 + 1];
    __shared__ float Bs[KC][64 + 1];
    int row0 = blockIdx.x * 64;
    int col0 = blockIdx.y * 64;
    int tid = threadIdx.x;
    int tx = tid & 15, ty = tid >> 4;
    float acc[4][4] = {};
    for (int kc = 0; kc < K; kc += KC) {
        #pragma unroll
        for (int i = 0; i < 8; i++) {
            int idx = tid + i * 256;           // 64x32 A tile
            int m = idx >> 5, k = idx & 31;
            int r = row0 + m;
            As[k][m] = (r < M) ? A[(size_t)r * K + kc + k] : 0.f;
        }
        #pragma unroll
        for (int i = 0; i < 8; i++) {
            int idx = tid + i * 256;           // 32x64 B tile
            int k = idx >> 6, c = idx & 63;
            Bs[k][c] = B[(size_t)(kc + k) * N + col0 + c];
        }
        __syncthreads();
        #pragma unroll
        for (int kk = 0; kk < KC; kk++) {
            float a[4], b[4];
            #pragma unroll
            for (int i = 0; i < 4; i++) a[i] = As[kk][ty * 4 + i];
            #pragma unroll
            for (int j = 0; j < 4; j++) b[j] = Bs[kk][tx * 4 + j];
            #pragma unroll
            for (int i = 0; i < 4; i++)
                #pragma unroll
                for (int j = 0; j < 4; j++) acc[i][j] += a[i] * b[j];
        }
        __syncthreads();
    }
    #pragma unroll
    for (int i = 0; i < 4; i++) {
        int r = row0 + ty * 4 + i;
        if (r < M) {
            #pragma unroll
            for (int j = 0; j < 4; j++)
                C[(size_t)r * N + col0 + tx * 4 + j] = acc[i][j];
        }
    }
}

// ---------- el/er layer1: feat [N,256] (4 heads x 64), wave per node ----------
__global__ __launch_bounds__(256) void elr1_kernel(const float* __restrict__ feat,
                                                   const float* __restrict__ al,
                                                   const float* __restrict__ ar,
                                                   float* __restrict__ el,
                                                   float* __restrict__ er, int N) {
    int wave = (blockIdx.x * 256 + threadIdx.x) >> 6;
    int lane = threadIdx.x & 63;
    if (wave >= N) return;
    const float4 f = *(const float4*)(feat + (size_t)wave * 256 + lane * 4);
    int h = lane >> 4;
    int d0 = (lane & 15) * 4;
    const float4 a = *(const float4*)(al + h * 64 + d0);
    const float4 b = *(const float4*)(ar + h * 64 + d0);
    float dl = f.x * a.x + f.y * a.y + f.z * a.z + f.w * a.w;
    float dr = f.x * b.x + f.y * b.y + f.z * b.z + f.w * b.w;
    #pragma unroll
    for (int off = 1; off < 16; off <<= 1) {
        dl += __shfl_xor(dl, off);
        dr += __shfl_xor(dr, off);
    }
    if ((lane & 15) == 0) {
        el[wave * 4 + h] = dl;
        er[wave * 4 + h] = dr;
    }
}

// ---------- el/er layer2: feat [N,64], wave per node ----------
__global__ __launch_bounds__(256) void elr2_kernel(const float* __restrict__ feat,
                                                   const float* __restrict__ al,
                                                   const float* __restrict__ ar,
                                                   float* __restrict__ el,
                                                   float* __restrict__ er, int N) {
    int wave = (blockIdx.x * 256 + threadIdx.x) >> 6;
    int lane = threadIdx.x & 63;
    if (wave >= N) return;
    float f = feat[(size_t)wave * 64 + lane];
    float dl = f * al[lane], dr = f * ar[lane];
    #pragma unroll
    for (int off = 1; off < 64; off <<= 1) {
        dl += __shfl_xor(dl, off);
        dr += __shfl_xor(dr, off);
    }
    if (lane == 0) { el[wave] = dl; er[wave] = dr; }
}

// ---------- layer1 fused per-node: softmax + aggregate + bias + relu ----------
// one wave per node; lane: h = lane>>4, d4 = lane&15 (4 floats each)
__global__ __launch_bounds__(256) void gat1_node(const float* __restrict__ feat,
                                                 const float* __restrict__ el,
                                                 const float* __restrict__ er,
                                                 const int* __restrict__ rowptr,
                                                 const int* __restrict__ csr_src,
                                                 const float* __restrict__ bias,
                                                 float* __restrict__ out, int N) {
    int node = (blockIdx.x * 256 + threadIdx.x) >> 6;
    int lane = threadIdx.x & 63;
    if (node >= N) return;
    int h = lane >> 4;
    int beg = rowptr[node], end = rowptr[node + 1];
    float erd = er[(size_t)node * 4 + h];
    float m = -1e30f;
    for (int k = beg; k < end; k++) {
        int s = csr_src[k];
        float sc = el[(size_t)s * 4 + h] + erd;
        sc = sc > 0.f ? sc : NEG_SLOPE * sc;
        m = fmaxf(m, sc);
    }
    float den = 0.f;
    float4 acc = {0.f, 0.f, 0.f, 0.f};
    for (int k = beg; k < end; k++) {
        int s = csr_src[k];
        float sc = el[(size_t)s * 4 + h] + erd;
        sc = sc > 0.f ? sc : NEG_SLOPE * sc;
        float w = __expf(sc - m);
        den += w;
        float4 f = *(const float4*)(feat + (size_t)s * 256 + lane * 4);
        acc.x += w * f.x; acc.y += w * f.y; acc.z += w * f.z; acc.w += w * f.w;
    }
    float inv = (den > 0.f) ? 1.f / den : 0.f;
    float4 b = *(const float4*)(bias + lane * 4);
    float4 o;
    o.x = fmaxf(acc.x * inv + b.x, 0.f);
    o.y = fmaxf(acc.y * inv + b.y, 0.f);
    o.z = fmaxf(acc.z * inv + b.z, 0.f);
    o.w = fmaxf(acc.w * inv + b.w, 0.f);
    *(float4*)(out + (size_t)node * 256 + lane * 4) = o;
}

// ---------- layer2 fused per-node: softmax + aggregate + bias + relu + row-sum ----------
__global__ __launch_bounds__(256) void gat2_node(const float* __restrict__ feat,
                                                 const float* __restrict__ el,
                                                 const float* __restrict__ er,
                                                 const int* __restrict__ rowptr,
                                                 const int* __restrict__ csr_src,
                                                 const float* __restrict__ bias,
                                                 float* __restrict__ emb,
                                                 float* __restrict__ go, int N) {
    int node = (blockIdx.x * 256 + threadIdx.x) >> 6;
    int lane = threadIdx.x & 63;
    if (node >= N) return;
    int beg = rowptr[node], end = rowptr[node + 1];
    float erd = er[node];
    float m = -1e30f;
    for (int k = beg; k < end; k++) {
        int s = csr_src[k];
        float sc = el[s] + erd;
        sc = sc > 0.f ? sc : NEG_SLOPE * sc;
        m = fmaxf(m, sc);
    }
    float den = 0.f, acc = 0.f;
    for (int k = beg; k < end; k++) {
        int s = csr_src[k];
        float sc = el[s] + erd;
        sc = sc > 0.f ? sc : NEG_SLOPE * sc;
        float w = __expf(sc - m);
        den += w;
        acc += w * feat[(size_t)s * 64 + lane];
    }
    float inv = (den > 0.f) ? 1.f / den : 0.f;
    float v = fmaxf(acc * inv + bias[lane], 0.f);
    go[(size_t)node * 64 + lane] = v;
    float sum = v;
    #pragma unroll
    for (int off = 1; off < 64; off <<= 1) sum += __shfl_xor(sum, off);
    if (lane == 0) emb[node] = sum;
}

extern "C" void kernel_launch(void* const* d_in, const int* in_sizes, int n_in,
                              void* d_out, int out_size, void* d_ws, size_t ws_size,
                              hipStream_t stream) {
    const float* x   = (const float*)d_in[0];
    const int*   src = (const int*)d_in[1];
    const int*   dst = (const int*)d_in[2];
    const float* W1  = (const float*)d_in[3];
    const float* al1 = (const float*)d_in[4];
    const float* ar1 = (const float*)d_in[5];
    const float* b1  = (const float*)d_in[6];
    const float* W2  = (const float*)d_in[7];
    const float* al2 = (const float*)d_in[8];
    const float* ar2 = (const float*)d_in[9];
    const float* b2  = (const float*)d_in[10];
    const int N = in_sizes[0] / 128;
    const int E = in_sizes[1];
    const int NB = (N + 255) / 256;

    float* ws = (float*)d_ws;
    size_t off = 0;
    auto alloc = [&](size_t n) { size_t o = off; off += (n + 63) & ~(size_t)63; return o; };
    size_t feat1  = alloc((size_t)N * 256);
    size_t out1   = alloc((size_t)N * 256);
    size_t feat2  = alloc((size_t)N * 64);
    size_t el1    = alloc((size_t)N * 4);
    size_t er1    = alloc((size_t)N * 4);
    size_t el2    = alloc((size_t)N);
    size_t er2    = alloc((size_t)N);
    size_t counts = alloc((size_t)N);
    size_t cursor = alloc((size_t)N);
    size_t bsum   = alloc((size_t)NB + 64);
    size_t rowp   = alloc((size_t)N + 1);
    size_t csrs   = alloc((size_t)E);
    (void)ws_size;

    int* icounts = (int*)(ws + counts);
    int* icursor = (int*)(ws + cursor);
    int* ibsum   = (int*)(ws + bsum);
    int* irowp   = (int*)(ws + rowp);
    int* icsrs   = (int*)(ws + csrs);

    // --- CSR build (dst-indexed) ---
    zero_kernel<<<128, 256, 0, stream>>>(icounts, N);
    zero_kernel<<<128, 256, 0, stream>>>(icursor, N);
    hist_kernel<<<(E + 255) / 256, 256, 0, stream>>>(dst, icounts, E);
    bsum_kernel<<<NB, 256, 0, stream>>>(icounts, ibsum, N);
    bscan_kernel<<<1, 256, 0, stream>>>(ibsum, NB, irowp, N, E);
    rowptr_kernel<<<NB, 256, 0, stream>>>(icounts, ibsum, irowp, N);
    fill_kernel<<<(E + 255) / 256, 256, 0, stream>>>(src, dst, irowp, icursor, icsrs, E);

    // --- layer 1 ---
    dim3 g1((N + 63) / 64, 4);
    gemm_tile<<<g1, 256, 0, stream>>>(x, W1, ws + feat1, N, 256, 128);
    elr1_kernel<<<(N + 3) / 4, 256, 0, stream>>>(ws + feat1, al1, ar1, ws + el1, ws + er1, N);
    gat1_node<<<(N + 3) / 4, 256, 0, stream>>>(ws + feat1, ws + el1, ws + er1,
                                               irowp, icsrs, b1, ws + out1, N);

    // --- layer 2 ---
    dim3 g2((N + 63) / 64, 1);
    gemm_tile<<<g2, 256, 0, stream>>>(ws + out1, W2, ws + feat2, N, 64, 256);
    elr2_kernel<<<(N + 3) / 4, 256, 0, stream>>>(ws + feat2, al2, ar2, ws + el2, ws + er2, N);
    gat2_node<<<(N + 3) / 4, 256, 0, stream>>>(ws + feat2, ws + el2, ws + er2,
                                               irowp, icsrs, b2, (float*)d_out,
                                               (float*)d_out + N, N);
}

// Round 3
// 440.019 us; speedup vs baseline: 8.9176x; 1.2297x over previous
//
#include <hip/hip_runtime.h>
#include <hip/hip_bf16.h>

#define NEG_SLOPE 0.2f

typedef __attribute__((ext_vector_type(8))) short short8v;
typedef __attribute__((ext_vector_type(4))) float f32x4;

// ---------- bf16 round-to-nearest helpers ----------
__device__ __forceinline__ unsigned short f2bf(float f) {
    unsigned u = __float_as_uint(f);
    unsigned r = (u + 0x7FFFu + ((u >> 16) & 1u)) >> 16;
    return (unsigned short)r;
}
__device__ __forceinline__ float bf2f(unsigned short h) {
    return __uint_as_float((unsigned)h << 16);
}

// ---------- zero ints ----------
__global__ __launch_bounds__(256) void zero_kernel(int* p, int n) {
    int i = blockIdx.x * 256 + threadIdx.x;
    int stride = gridDim.x * 256;
    for (int k = i; k < n; k += stride) p[k] = 0;
}

// ---------- CSR build ----------
__global__ __launch_bounds__(256) void hist_kernel(const int* __restrict__ dst,
                                                   int* __restrict__ counts, int E) {
    int e = blockIdx.x * 256 + threadIdx.x;
    if (e < E) atomicAdd(counts + dst[e], 1);
}

__global__ __launch_bounds__(256) void bsum_kernel(const int* __restrict__ counts,
                                                   int* __restrict__ bsum, int N) {
    __shared__ int sh[256];
    int i = blockIdx.x * 256 + threadIdx.x;
    int v = (i < N) ? counts[i] : 0;
    sh[threadIdx.x] = v;
    __syncthreads();
    for (int off = 128; off > 0; off >>= 1) {
        if (threadIdx.x < off) sh[threadIdx.x] += sh[threadIdx.x + off];
        __syncthreads();
    }
    if (threadIdx.x == 0) bsum[blockIdx.x] = sh[0];
}

__global__ __launch_bounds__(256) void bscan_kernel(int* __restrict__ bsum, int nb,
                                                    int* __restrict__ rowptr, int N, int E) {
    __shared__ int sh[256];
    int tid = threadIdx.x;
    int carry = 0;
    for (int base = 0; base < nb; base += 256) {
        int i = base + tid;
        int v = (i < nb) ? bsum[i] : 0;
        sh[tid] = v;
        __syncthreads();
        for (int off = 1; off < 256; off <<= 1) {
            int t = (tid >= off) ? sh[tid - off] : 0;
            __syncthreads();
            sh[tid] += t;
            __syncthreads();
        }
        if (i < nb) bsum[i] = carry + sh[tid] - v;  // exclusive
        int tot = sh[255];
        __syncthreads();
        carry += tot;
    }
    if (tid == 0) rowptr[N] = E;
}

__global__ __launch_bounds__(256) void rowptr_kernel(const int* __restrict__ counts,
                                                     const int* __restrict__ bsum,
                                                     int* __restrict__ rowptr, int N) {
    __shared__ int sh[256];
    int i = blockIdx.x * 256 + threadIdx.x;
    int tid = threadIdx.x;
    int v = (i < N) ? counts[i] : 0;
    sh[tid] = v;
    __syncthreads();
    for (int off = 1; off < 256; off <<= 1) {
        int t = (tid >= off) ? sh[tid - off] : 0;
        __syncthreads();
        sh[tid] += t;
        __syncthreads();
    }
    if (i < N) rowptr[i] = bsum[blockIdx.x] + sh[tid] - v;  // exclusive
}

__global__ __launch_bounds__(256) void fill_kernel(const int* __restrict__ src,
                                                   const int* __restrict__ dst,
                                                   const int* __restrict__ rowptr,
                                                   int* __restrict__ cursor,
                                                   int* __restrict__ csr_src, int E) {
    int e = blockIdx.x * 256 + threadIdx.x;
    if (e >= E) return;
    int d = dst[e];
    int pos = atomicAdd(cursor + d, 1);
    csr_src[rowptr[d] + pos] = src[e];
}

// ---------- split fp32 -> bf16 hi/lo (contiguous) ----------
__global__ __launch_bounds__(256) void split_hl(const float* __restrict__ in,
                                                unsigned short* __restrict__ hi,
                                                unsigned short* __restrict__ lo, int n4) {
    int i = blockIdx.x * 256 + threadIdx.x;  // over float4s
    if (i >= n4) return;
    float4 v = *(const float4*)(in + (size_t)i * 4);
    ushort4 h, l;
    h.x = f2bf(v.x); l.x = f2bf(v.x - bf2f(h.x));
    h.y = f2bf(v.y); l.y = f2bf(v.y - bf2f(h.y));
    h.z = f2bf(v.z); l.z = f2bf(v.z - bf2f(h.z));
    h.w = f2bf(v.w); l.w = f2bf(v.w - bf2f(h.w));
    *(ushort4*)(hi + (size_t)i * 4) = h;
    *(ushort4*)(lo + (size_t)i * 4) = l;
}

// ---------- split + transpose W[K,Nn] -> Wt hi/lo [Nn,K] ----------
__global__ __launch_bounds__(256) void splitT_hl(const float* __restrict__ W,
                                                 unsigned short* __restrict__ hiT,
                                                 unsigned short* __restrict__ loT,
                                                 int K, int Nn) {
    int tid = blockIdx.x * 256 + threadIdx.x;
    if (tid >= K * Nn) return;
    int k = tid / Nn, n = tid % Nn;
    float f = W[tid];
    unsigned short h = f2bf(f);
    hiT[(size_t)n * K + k] = h;
    loT[(size_t)n * K + k] = f2bf(f - bf2f(h));
}

// ---------- MFMA GEMM: C[M,Nn] = A[M,K] @ Wt[Nn,K]^T, bf16 hi/lo x 3 ----------
// BM=64, BN=64, BK=128. Block 256 threads = 4 waves; wave w -> rows w*16..w*16+15.
__global__ __launch_bounds__(256) void gemm_mfma(const unsigned short* __restrict__ Ah_g,
                                                 const unsigned short* __restrict__ Al_g,
                                                 const unsigned short* __restrict__ Bh_g,
                                                 const unsigned short* __restrict__ Bl_g,
                                                 float* __restrict__ C,
                                                 int M, int Nn, int K) {
    __shared__ unsigned short Ah[64][136], Al[64][136], Bh[64][136], Bl[64][136];
    int tid = threadIdx.x;
    int row0 = blockIdx.x * 64;
    int col0 = blockIdx.y * 64;
    int wv = tid >> 6;
    int lane = tid & 63;
    int l15 = lane & 15;
    int kgrp = (lane >> 4) * 8;

    f32x4 acc[4] = {{0.f,0.f,0.f,0.f},{0.f,0.f,0.f,0.f},{0.f,0.f,0.f,0.f},{0.f,0.f,0.f,0.f}};

    for (int kc = 0; kc < K; kc += 128) {
        __syncthreads();
        #pragma unroll
        for (int p = 0; p < 4; p++) {
            int idx = (p * 256 + tid) * 8;
            int r = idx >> 7;          // /128
            int c = idx & 127;
            int gr = row0 + r;
            uint4 vh = {0,0,0,0}, vl = {0,0,0,0};
            if (gr < M) {
                vh = *(const uint4*)(Ah_g + (size_t)gr * K + kc + c);
                vl = *(const uint4*)(Al_g + (size_t)gr * K + kc + c);
            }
            *(uint4*)&Ah[r][c] = vh;
            *(uint4*)&Al[r][c] = vl;
            // B tile: rows are output cols (Wt layout [Nn][K])
            uint4 wh = *(const uint4*)(Bh_g + (size_t)(col0 + r) * K + kc + c);
            uint4 wl = *(const uint4*)(Bl_g + (size_t)(col0 + r) * K + kc + c);
            *(uint4*)&Bh[r][c] = wh;
            *(uint4*)&Bl[r][c] = wl;
        }
        __syncthreads();
        #pragma unroll
        for (int kk = 0; kk < 4; kk++) {
            int kc0 = kk * 32 + kgrp;
            short8v ah = *(short8v*)&Ah[wv * 16 + l15][kc0];
            short8v al = *(short8v*)&Al[wv * 16 + l15][kc0];
            #pragma unroll
            for (int c = 0; c < 4; c++) {
                short8v bh = *(short8v*)&Bh[c * 16 + l15][kc0];
                short8v bl = *(short8v*)&Bl[c * 16 + l15][kc0];
                acc[c] = __builtin_amdgcn_mfma_f32_16x16x32_bf16(ah, bh, acc[c], 0, 0, 0);
                acc[c] = __builtin_amdgcn_mfma_f32_16x16x32_bf16(ah, bl, acc[c], 0, 0, 0);
                acc[c] = __builtin_amdgcn_mfma_f32_16x16x32_bf16(al, bh, acc[c], 0, 0, 0);
            }
        }
    }
    // C/D layout: col = lane&15, row = (lane>>4)*4 + j
    #pragma unroll
    for (int c = 0; c < 4; c++) {
        #pragma unroll
        for (int j = 0; j < 4; j++) {
            int r = row0 + wv * 16 + (lane >> 4) * 4 + j;
            if (r < M) C[(size_t)r * Nn + col0 + c * 16 + l15] = acc[c][j];
        }
    }
}

// ---------- el/er layer1: feat [N,256] (4 heads x 64), wave per node ----------
__global__ __launch_bounds__(256) void elr1_kernel(const float* __restrict__ feat,
                                                   const float* __restrict__ al,
                                                   const float* __restrict__ ar,
                                                   float* __restrict__ el,
                                                   float* __restrict__ er, int N) {
    int wave = (blockIdx.x * 256 + threadIdx.x) >> 6;
    int lane = threadIdx.x & 63;
    if (wave >= N) return;
    const float4 f = *(const float4*)(feat + (size_t)wave * 256 + lane * 4);
    int h = lane >> 4;
    int d0 = (lane & 15) * 4;
    const float4 a = *(const float4*)(al + h * 64 + d0);
    const float4 b = *(const float4*)(ar + h * 64 + d0);
    float dl = f.x * a.x + f.y * a.y + f.z * a.z + f.w * a.w;
    float dr = f.x * b.x + f.y * b.y + f.z * b.z + f.w * b.w;
    #pragma unroll
    for (int off = 1; off < 16; off <<= 1) {
        dl += __shfl_xor(dl, off);
        dr += __shfl_xor(dr, off);
    }
    if ((lane & 15) == 0) {
        el[wave * 4 + h] = dl;
        er[wave * 4 + h] = dr;
    }
}

// ---------- el/er layer2: feat [N,64], wave per node ----------
__global__ __launch_bounds__(256) void elr2_kernel(const float* __restrict__ feat,
                                                   const float* __restrict__ al,
                                                   const float* __restrict__ ar,
                                                   float* __restrict__ el,
                                                   float* __restrict__ er, int N) {
    int wave = (blockIdx.x * 256 + threadIdx.x) >> 6;
    int lane = threadIdx.x & 63;
    if (wave >= N) return;
    float f = feat[(size_t)wave * 64 + lane];
    float dl = f * al[lane], dr = f * ar[lane];
    #pragma unroll
    for (int off = 1; off < 64; off <<= 1) {
        dl += __shfl_xor(dl, off);
        dr += __shfl_xor(dr, off);
    }
    if (lane == 0) { el[wave] = dl; er[wave] = dr; }
}

// ---------- layer1 fused per-node: softmax + aggregate + bias + relu ----------
// one wave per node; output written directly as bf16 hi/lo (GEMM2's A operand)
__global__ __launch_bounds__(256) void gat1_node(const float* __restrict__ feat,
                                                 const float* __restrict__ el,
                                                 const float* __restrict__ er,
                                                 const int* __restrict__ rowptr,
                                                 const int* __restrict__ csr_src,
                                                 const float* __restrict__ bias,
                                                 unsigned short* __restrict__ out_h,
                                                 unsigned short* __restrict__ out_l, int N) {
    int node = (blockIdx.x * 256 + threadIdx.x) >> 6;
    int lane = threadIdx.x & 63;
    if (node >= N) return;
    int h = lane >> 4;
    int beg = rowptr[node], end = rowptr[node + 1];
    float erd = er[(size_t)node * 4 + h];
    float m = -1e30f;
    for (int k = beg; k < end; k++) {
        int s = csr_src[k];
        float sc = el[(size_t)s * 4 + h] + erd;
        sc = sc > 0.f ? sc : NEG_SLOPE * sc;
        m = fmaxf(m, sc);
    }
    float den = 0.f;
    float4 acc = {0.f, 0.f, 0.f, 0.f};
    for (int k = beg; k < end; k++) {
        int s = csr_src[k];
        float sc = el[(size_t)s * 4 + h] + erd;
        sc = sc > 0.f ? sc : NEG_SLOPE * sc;
        float w = __expf(sc - m);
        den += w;
        float4 f = *(const float4*)(feat + (size_t)s * 256 + lane * 4);
        acc.x += w * f.x; acc.y += w * f.y; acc.z += w * f.z; acc.w += w * f.w;
    }
    float inv = (den > 0.f) ? 1.f / den : 0.f;
    float4 b = *(const float4*)(bias + lane * 4);
    float4 o;
    o.x = fmaxf(acc.x * inv + b.x, 0.f);
    o.y = fmaxf(acc.y * inv + b.y, 0.f);
    o.z = fmaxf(acc.z * inv + b.z, 0.f);
    o.w = fmaxf(acc.w * inv + b.w, 0.f);
    ushort4 oh, ol;
    oh.x = f2bf(o.x); ol.x = f2bf(o.x - bf2f(oh.x));
    oh.y = f2bf(o.y); ol.y = f2bf(o.y - bf2f(oh.y));
    oh.z = f2bf(o.z); ol.z = f2bf(o.z - bf2f(oh.z));
    oh.w = f2bf(o.w); ol.w = f2bf(o.w - bf2f(oh.w));
    *(ushort4*)(out_h + (size_t)node * 256 + lane * 4) = oh;
    *(ushort4*)(out_l + (size_t)node * 256 + lane * 4) = ol;
}

// ---------- layer2 fused per-node: softmax + aggregate + bias + relu + row-sum ----------
__global__ __launch_bounds__(256) void gat2_node(const float* __restrict__ feat,
                                                 const float* __restrict__ el,
                                                 const float* __restrict__ er,
                                                 const int* __restrict__ rowptr,
                                                 const int* __restrict__ csr_src,
                                                 const float* __restrict__ bias,
                                                 float* __restrict__ emb,
                                                 float* __restrict__ go, int N) {
    int node = (blockIdx.x * 256 + threadIdx.x) >> 6;
    int lane = threadIdx.x & 63;
    if (node >= N) return;
    int beg = rowptr[node], end = rowptr[node + 1];
    float erd = er[node];
    float m = -1e30f;
    for (int k = beg; k < end; k++) {
        int s = csr_src[k];
        float sc = el[s] + erd;
        sc = sc > 0.f ? sc : NEG_SLOPE * sc;
        m = fmaxf(m, sc);
    }
    float den = 0.f, acc = 0.f;
    for (int k = beg; k < end; k++) {
        int s = csr_src[k];
        float sc = el[s] + erd;
        sc = sc > 0.f ? sc : NEG_SLOPE * sc;
        float w = __expf(sc - m);
        den += w;
        acc += w * feat[(size_t)s * 64 + lane];
    }
    float inv = (den > 0.f) ? 1.f / den : 0.f;
    float v = fmaxf(acc * inv + bias[lane], 0.f);
    go[(size_t)node * 64 + lane] = v;
    float sum = v;
    #pragma unroll
    for (int off = 1; off < 64; off <<= 1) sum += __shfl_xor(sum, off);
    if (lane == 0) emb[node] = sum;
}

extern "C" void kernel_launch(void* const* d_in, const int* in_sizes, int n_in,
                              void* d_out, int out_size, void* d_ws, size_t ws_size,
                              hipStream_t stream) {
    const float* x   = (const float*)d_in[0];
    const int*   src = (const int*)d_in[1];
    const int*   dst = (const int*)d_in[2];
    const float* W1  = (const float*)d_in[3];
    const float* al1 = (const float*)d_in[4];
    const float* ar1 = (const float*)d_in[5];
    const float* b1  = (const float*)d_in[6];
    const float* W2  = (const float*)d_in[7];
    const float* al2 = (const float*)d_in[8];
    const float* ar2 = (const float*)d_in[9];
    const float* b2  = (const float*)d_in[10];
    const int N = in_sizes[0] / 128;
    const int E = in_sizes[1];
    const int NB = (N + 255) / 256;

    char* base = (char*)d_ws;
    size_t off = 0;
    auto alloc = [&](size_t bytes) {
        off = (off + 255) & ~(size_t)255;
        void* p = base + off;
        off += bytes;
        return p;
    };
    float* feat1 = (float*)alloc((size_t)N * 256 * 4);
    float* feat2 = (float*)alloc((size_t)N * 64 * 4);
    float* el1   = (float*)alloc((size_t)N * 4 * 4);
    float* er1   = (float*)alloc((size_t)N * 4 * 4);
    float* el2   = (float*)alloc((size_t)N * 4);
    float* er2   = (float*)alloc((size_t)N * 4);
    int* icounts = (int*)alloc((size_t)N * 4);
    int* icursor = (int*)alloc((size_t)N * 4);
    int* ibsum   = (int*)alloc((size_t)(NB + 1) * 4);
    int* irowp   = (int*)alloc((size_t)(N + 1) * 4);
    int* icsrs   = (int*)alloc((size_t)E * 4);
    unsigned short* xh   = (unsigned short*)alloc((size_t)N * 128 * 2);
    unsigned short* xl   = (unsigned short*)alloc((size_t)N * 128 * 2);
    unsigned short* w1th = (unsigned short*)alloc((size_t)128 * 256 * 2);
    unsigned short* w1tl = (unsigned short*)alloc((size_t)128 * 256 * 2);
    unsigned short* hh   = (unsigned short*)alloc((size_t)N * 256 * 2);
    unsigned short* hl   = (unsigned short*)alloc((size_t)N * 256 * 2);
    unsigned short* w2th = (unsigned short*)alloc((size_t)256 * 64 * 2);
    unsigned short* w2tl = (unsigned short*)alloc((size_t)256 * 64 * 2);
    (void)ws_size;

    // --- CSR build (dst-indexed) ---
    zero_kernel<<<128, 256, 0, stream>>>(icounts, N);
    zero_kernel<<<128, 256, 0, stream>>>(icursor, N);
    hist_kernel<<<(E + 255) / 256, 256, 0, stream>>>(dst, icounts, E);
    bsum_kernel<<<NB, 256, 0, stream>>>(icounts, ibsum, N);
    bscan_kernel<<<1, 256, 0, stream>>>(ibsum, NB, irowp, N, E);
    rowptr_kernel<<<NB, 256, 0, stream>>>(icounts, ibsum, irowp, N);
    fill_kernel<<<(E + 255) / 256, 256, 0, stream>>>(src, dst, irowp, icursor, icsrs, E);

    // --- input/weight splits ---
    split_hl<<<(N * 128 / 4 + 255) / 256, 256, 0, stream>>>(x, xh, xl, N * 128 / 4);
    splitT_hl<<<(128 * 256 + 255) / 256, 256, 0, stream>>>(W1, w1th, w1tl, 128, 256);
    splitT_hl<<<(256 * 64 + 255) / 256, 256, 0, stream>>>(W2, w2th, w2tl, 256, 64);

    // --- layer 1 ---
    {
        dim3 g((N + 63) / 64, 256 / 64);
        gemm_mfma<<<g, 256, 0, stream>>>(xh, xl, w1th, w1tl, feat1, N, 256, 128);
    }
    elr1_kernel<<<(N + 3) / 4, 256, 0, stream>>>(feat1, al1, ar1, el1, er1, N);
    gat1_node<<<(N + 3) / 4, 256, 0, stream>>>(feat1, el1, er1, irowp, icsrs, b1, hh, hl, N);

    // --- layer 2 ---
    {
        dim3 g((N + 63) / 64, 1);
        gemm_mfma<<<g, 256, 0, stream>>>(hh, hl, w2th, w2tl, feat2, N, 64, 256);
    }
    elr2_kernel<<<(N + 3) / 4, 256, 0, stream>>>(feat2, al2, ar2, el2, er2, N);
    gat2_node<<<(N + 3) / 4, 256, 0, stream>>>(feat2, el2, er2, irowp, icsrs, b2,
                                               (float*)d_out, (float*)d_out + N, N);
}

// Round 4
// 357.501 us; speedup vs baseline: 10.9759x; 1.2308x over previous
//
#include <hip/hip_runtime.h>
#include <hip/hip_bf16.h>

#define NEG_SLOPE 0.2f

typedef __attribute__((ext_vector_type(8))) short short8v;
typedef __attribute__((ext_vector_type(4))) float f32x4;

// ---------- bf16 round-to-nearest helpers ----------
__device__ __forceinline__ unsigned short f2bf(float f) {
    unsigned u = __float_as_uint(f);
    unsigned r = (u + 0x7FFFu + ((u >> 16) & 1u)) >> 16;
    return (unsigned short)r;
}
__device__ __forceinline__ float bf2f(unsigned short h) {
    return __uint_as_float((unsigned)h << 16);
}

// ---------- zero ints ----------
__global__ __launch_bounds__(256) void zero_kernel(int* p, int n) {
    int i = blockIdx.x * 256 + threadIdx.x;
    int stride = gridDim.x * 256;
    for (int k = i; k < n; k += stride) p[k] = 0;
}

// ---------- CSR build ----------
__global__ __launch_bounds__(256) void hist_kernel(const int* __restrict__ dst,
                                                   int* __restrict__ counts, int E) {
    int e = blockIdx.x * 256 + threadIdx.x;
    if (e < E) atomicAdd(counts + dst[e], 1);
}

__global__ __launch_bounds__(256) void bsum_kernel(const int* __restrict__ counts,
                                                   int* __restrict__ bsum, int N) {
    __shared__ int sh[256];
    int i = blockIdx.x * 256 + threadIdx.x;
    int v = (i < N) ? counts[i] : 0;
    sh[threadIdx.x] = v;
    __syncthreads();
    for (int off = 128; off > 0; off >>= 1) {
        if (threadIdx.x < off) sh[threadIdx.x] += sh[threadIdx.x + off];
        __syncthreads();
    }
    if (threadIdx.x == 0) bsum[blockIdx.x] = sh[0];
}

__global__ __launch_bounds__(256) void bscan_kernel(int* __restrict__ bsum, int nb,
                                                    int* __restrict__ rowptr, int N, int E) {
    __shared__ int sh[256];
    int tid = threadIdx.x;
    int carry = 0;
    for (int base = 0; base < nb; base += 256) {
        int i = base + tid;
        int v = (i < nb) ? bsum[i] : 0;
        sh[tid] = v;
        __syncthreads();
        for (int off = 1; off < 256; off <<= 1) {
            int t = (tid >= off) ? sh[tid - off] : 0;
            __syncthreads();
            sh[tid] += t;
            __syncthreads();
        }
        if (i < nb) bsum[i] = carry + sh[tid] - v;  // exclusive
        int tot = sh[255];
        __syncthreads();
        carry += tot;
    }
    if (tid == 0) rowptr[N] = E;
}

__global__ __launch_bounds__(256) void rowptr_kernel(const int* __restrict__ counts,
                                                     const int* __restrict__ bsum,
                                                     int* __restrict__ rowptr, int N) {
    __shared__ int sh[256];
    int i = blockIdx.x * 256 + threadIdx.x;
    int tid = threadIdx.x;
    int v = (i < N) ? counts[i] : 0;
    sh[tid] = v;
    __syncthreads();
    for (int off = 1; off < 256; off <<= 1) {
        int t = (tid >= off) ? sh[tid - off] : 0;
        __syncthreads();
        sh[tid] += t;
        __syncthreads();
    }
    if (i < N) rowptr[i] = bsum[blockIdx.x] + sh[tid] - v;  // exclusive
}

__global__ __launch_bounds__(256) void fill_kernel(const int* __restrict__ src,
                                                   const int* __restrict__ dst,
                                                   const int* __restrict__ rowptr,
                                                   int* __restrict__ cursor,
                                                   int* __restrict__ csr_src, int E) {
    int e = blockIdx.x * 256 + threadIdx.x;
    if (e >= E) return;
    int d = dst[e];
    int pos = atomicAdd(cursor + d, 1);
    csr_src[rowptr[d] + pos] = src[e];
}

// ---------- split fp32 -> bf16 hi/lo (contiguous) ----------
__global__ __launch_bounds__(256) void split_hl(const float* __restrict__ in,
                                                unsigned short* __restrict__ hi,
                                                unsigned short* __restrict__ lo, int n4) {
    int i = blockIdx.x * 256 + threadIdx.x;  // over float4s
    if (i >= n4) return;
    float4 v = *(const float4*)(in + (size_t)i * 4);
    ushort4 h, l;
    h.x = f2bf(v.x); l.x = f2bf(v.x - bf2f(h.x));
    h.y = f2bf(v.y); l.y = f2bf(v.y - bf2f(h.y));
    h.z = f2bf(v.z); l.z = f2bf(v.z - bf2f(h.z));
    h.w = f2bf(v.w); l.w = f2bf(v.w - bf2f(h.w));
    *(ushort4*)(hi + (size_t)i * 4) = h;
    *(ushort4*)(lo + (size_t)i * 4) = l;
}

// ---------- split + transpose W[K,Nn] -> Wt hi/lo [Nn,K] ----------
__global__ __launch_bounds__(256) void splitT_hl(const float* __restrict__ W,
                                                 unsigned short* __restrict__ hiT,
                                                 unsigned short* __restrict__ loT,
                                                 int K, int Nn) {
    int tid = blockIdx.x * 256 + threadIdx.x;
    if (tid >= K * Nn) return;
    int k = tid / Nn, n = tid % Nn;
    float f = W[tid];
    unsigned short h = f2bf(f);
    hiT[(size_t)n * K + k] = h;
    loT[(size_t)n * K + k] = f2bf(f - bf2f(h));
}

// ---------- MFMA GEMM: C[M,Nn](bf16) = A[M,K] @ Wt[Nn,K]^T, bf16 hi/lo x 3 ----------
// BM=64, BN=64, BK=128. Block 256 threads = 4 waves; wave w -> rows w*16..w*16+15.
__global__ __launch_bounds__(256) void gemm_mfma(const unsigned short* __restrict__ Ah_g,
                                                 const unsigned short* __restrict__ Al_g,
                                                 const unsigned short* __restrict__ Bh_g,
                                                 const unsigned short* __restrict__ Bl_g,
                                                 unsigned short* __restrict__ C,
                                                 int M, int Nn, int K) {
    __shared__ unsigned short Ah[64][136], Al[64][136], Bh[64][136], Bl[64][136];
    int tid = threadIdx.x;
    int row0 = blockIdx.x * 64;
    int col0 = blockIdx.y * 64;
    int wv = tid >> 6;
    int lane = tid & 63;
    int l15 = lane & 15;
    int kgrp = (lane >> 4) * 8;

    f32x4 acc[4] = {{0.f,0.f,0.f,0.f},{0.f,0.f,0.f,0.f},{0.f,0.f,0.f,0.f},{0.f,0.f,0.f,0.f}};

    for (int kc = 0; kc < K; kc += 128) {
        __syncthreads();
        #pragma unroll
        for (int p = 0; p < 4; p++) {
            int idx = (p * 256 + tid) * 8;
            int r = idx >> 7;          // /128
            int c = idx & 127;
            int gr = row0 + r;
            uint4 vh = {0,0,0,0}, vl = {0,0,0,0};
            if (gr < M) {
                vh = *(const uint4*)(Ah_g + (size_t)gr * K + kc + c);
                vl = *(const uint4*)(Al_g + (size_t)gr * K + kc + c);
            }
            *(uint4*)&Ah[r][c] = vh;
            *(uint4*)&Al[r][c] = vl;
            // B tile: rows are output cols (Wt layout [Nn][K])
            uint4 wh = *(const uint4*)(Bh_g + (size_t)(col0 + r) * K + kc + c);
            uint4 wl = *(const uint4*)(Bl_g + (size_t)(col0 + r) * K + kc + c);
            *(uint4*)&Bh[r][c] = wh;
            *(uint4*)&Bl[r][c] = wl;
        }
        __syncthreads();
        #pragma unroll
        for (int kk = 0; kk < 4; kk++) {
            int kc0 = kk * 32 + kgrp;
            short8v ah = *(short8v*)&Ah[wv * 16 + l15][kc0];
            short8v al = *(short8v*)&Al[wv * 16 + l15][kc0];
            #pragma unroll
            for (int c = 0; c < 4; c++) {
                short8v bh = *(short8v*)&Bh[c * 16 + l15][kc0];
                short8v bl = *(short8v*)&Bl[c * 16 + l15][kc0];
                acc[c] = __builtin_amdgcn_mfma_f32_16x16x32_bf16(ah, bh, acc[c], 0, 0, 0);
                acc[c] = __builtin_amdgcn_mfma_f32_16x16x32_bf16(ah, bl, acc[c], 0, 0, 0);
                acc[c] = __builtin_amdgcn_mfma_f32_16x16x32_bf16(al, bh, acc[c], 0, 0, 0);
            }
        }
    }
    // C/D layout: col = lane&15, row = (lane>>4)*4 + j
    #pragma unroll
    for (int c = 0; c < 4; c++) {
        #pragma unroll
        for (int j = 0; j < 4; j++) {
            int r = row0 + wv * 16 + (lane >> 4) * 4 + j;
            if (r < M) C[(size_t)r * Nn + col0 + c * 16 + l15] = f2bf(acc[c][j]);
        }
    }
}

// ---------- el/er layer1: feat bf16 [N,256] (4 heads x 64), wave per node ----------
__global__ __launch_bounds__(256) void elr1_kernel(const unsigned short* __restrict__ feat,
                                                   const float* __restrict__ al,
                                                   const float* __restrict__ ar,
                                                   float* __restrict__ el,
                                                   float* __restrict__ er, int N) {
    int wave = (blockIdx.x * 256 + threadIdx.x) >> 6;
    int lane = threadIdx.x & 63;
    if (wave >= N) return;
    ushort4 fu = *(const ushort4*)(feat + (size_t)wave * 256 + lane * 4);
    float4 f = {bf2f(fu.x), bf2f(fu.y), bf2f(fu.z), bf2f(fu.w)};
    int h = lane >> 4;
    int d0 = (lane & 15) * 4;
    const float4 a = *(const float4*)(al + h * 64 + d0);
    const float4 b = *(const float4*)(ar + h * 64 + d0);
    float dl = f.x * a.x + f.y * a.y + f.z * a.z + f.w * a.w;
    float dr = f.x * b.x + f.y * b.y + f.z * b.z + f.w * b.w;
    #pragma unroll
    for (int off = 1; off < 16; off <<= 1) {
        dl += __shfl_xor(dl, off);
        dr += __shfl_xor(dr, off);
    }
    if ((lane & 15) == 0) {
        el[wave * 4 + h] = dl;
        er[wave * 4 + h] = dr;
    }
}

// ---------- el/er layer2: feat bf16 [N,64], wave per node ----------
__global__ __launch_bounds__(256) void elr2_kernel(const unsigned short* __restrict__ feat,
                                                   const float* __restrict__ al,
                                                   const float* __restrict__ ar,
                                                   float* __restrict__ el,
                                                   float* __restrict__ er, int N) {
    int wave = (blockIdx.x * 256 + threadIdx.x) >> 6;
    int lane = threadIdx.x & 63;
    if (wave >= N) return;
    float f = bf2f(feat[(size_t)wave * 64 + lane]);
    float dl = f * al[lane], dr = f * ar[lane];
    #pragma unroll
    for (int off = 1; off < 64; off <<= 1) {
        dl += __shfl_xor(dl, off);
        dr += __shfl_xor(dr, off);
    }
    if (lane == 0) { el[wave] = dl; er[wave] = dr; }
}

// ---------- layer1 fused per-node: softmax + aggregate + bias + relu ----------
// one wave per node; bf16 feat gather, unroll x2; out as bf16 hi/lo for GEMM2
__global__ __launch_bounds__(256) void gat1_node(const unsigned short* __restrict__ feat,
                                                 const float* __restrict__ el,
                                                 const float* __restrict__ er,
                                                 const int* __restrict__ rowptr,
                                                 const int* __restrict__ csr_src,
                                                 const float* __restrict__ bias,
                                                 unsigned short* __restrict__ out_h,
                                                 unsigned short* __restrict__ out_l, int N) {
    int node = (blockIdx.x * 256 + threadIdx.x) >> 6;
    int lane = threadIdx.x & 63;
    if (node >= N) return;
    int h = lane >> 4;
    int beg = rowptr[node], end = rowptr[node + 1];
    float erd = er[(size_t)node * 4 + h];
    float m = -1e30f;
    for (int k = beg; k < end; k++) {
        int s = csr_src[k];
        float sc = el[(size_t)s * 4 + h] + erd;
        sc = sc > 0.f ? sc : NEG_SLOPE * sc;
        m = fmaxf(m, sc);
    }
    float den = 0.f;
    float4 acc = {0.f, 0.f, 0.f, 0.f};
    int k = beg;
    for (; k + 1 < end; k += 2) {
        int s0 = csr_src[k], s1 = csr_src[k + 1];
        float sc0 = el[(size_t)s0 * 4 + h] + erd;
        float sc1 = el[(size_t)s1 * 4 + h] + erd;
        ushort4 f0 = *(const ushort4*)(feat + (size_t)s0 * 256 + lane * 4);
        ushort4 f1 = *(const ushort4*)(feat + (size_t)s1 * 256 + lane * 4);
        sc0 = sc0 > 0.f ? sc0 : NEG_SLOPE * sc0;
        sc1 = sc1 > 0.f ? sc1 : NEG_SLOPE * sc1;
        float w0 = __expf(sc0 - m), w1 = __expf(sc1 - m);
        den += w0 + w1;
        acc.x += w0 * bf2f(f0.x) + w1 * bf2f(f1.x);
        acc.y += w0 * bf2f(f0.y) + w1 * bf2f(f1.y);
        acc.z += w0 * bf2f(f0.z) + w1 * bf2f(f1.z);
        acc.w += w0 * bf2f(f0.w) + w1 * bf2f(f1.w);
    }
    if (k < end) {
        int s = csr_src[k];
        float sc = el[(size_t)s * 4 + h] + erd;
        sc = sc > 0.f ? sc : NEG_SLOPE * sc;
        float w = __expf(sc - m);
        ushort4 f = *(const ushort4*)(feat + (size_t)s * 256 + lane * 4);
        den += w;
        acc.x += w * bf2f(f.x);
        acc.y += w * bf2f(f.y);
        acc.z += w * bf2f(f.z);
        acc.w += w * bf2f(f.w);
    }
    float inv = (den > 0.f) ? 1.f / den : 0.f;
    float4 b = *(const float4*)(bias + lane * 4);
    float4 o;
    o.x = fmaxf(acc.x * inv + b.x, 0.f);
    o.y = fmaxf(acc.y * inv + b.y, 0.f);
    o.z = fmaxf(acc.z * inv + b.z, 0.f);
    o.w = fmaxf(acc.w * inv + b.w, 0.f);
    ushort4 oh, ol;
    oh.x = f2bf(o.x); ol.x = f2bf(o.x - bf2f(oh.x));
    oh.y = f2bf(o.y); ol.y = f2bf(o.y - bf2f(oh.y));
    oh.z = f2bf(o.z); ol.z = f2bf(o.z - bf2f(oh.z));
    oh.w = f2bf(o.w); ol.w = f2bf(o.w - bf2f(oh.w));
    *(ushort4*)(out_h + (size_t)node * 256 + lane * 4) = oh;
    *(ushort4*)(out_l + (size_t)node * 256 + lane * 4) = ol;
}

// ---------- layer2 fused per-node: softmax + aggregate + bias + relu + row-sum ----------
__global__ __launch_bounds__(256) void gat2_node(const unsigned short* __restrict__ feat,
                                                 const float* __restrict__ el,
                                                 const float* __restrict__ er,
                                                 const int* __restrict__ rowptr,
                                                 const int* __restrict__ csr_src,
                                                 const float* __restrict__ bias,
                                                 float* __restrict__ emb,
                                                 float* __restrict__ go, int N) {
    int node = (blockIdx.x * 256 + threadIdx.x) >> 6;
    int lane = threadIdx.x & 63;
    if (node >= N) return;
    int beg = rowptr[node], end = rowptr[node + 1];
    float erd = er[node];
    float m = -1e30f;
    for (int k = beg; k < end; k++) {
        int s = csr_src[k];
        float sc = el[s] + erd;
        sc = sc > 0.f ? sc : NEG_SLOPE * sc;
        m = fmaxf(m, sc);
    }
    float den = 0.f, acc = 0.f;
    int k = beg;
    for (; k + 3 < end; k += 4) {
        int s0 = csr_src[k], s1 = csr_src[k + 1], s2 = csr_src[k + 2], s3 = csr_src[k + 3];
        float sc0 = el[s0] + erd, sc1 = el[s1] + erd, sc2 = el[s2] + erd, sc3 = el[s3] + erd;
        unsigned short f0 = feat[(size_t)s0 * 64 + lane];
        unsigned short f1 = feat[(size_t)s1 * 64 + lane];
        unsigned short f2 = feat[(size_t)s2 * 64 + lane];
        unsigned short f3 = feat[(size_t)s3 * 64 + lane];
        sc0 = sc0 > 0.f ? sc0 : NEG_SLOPE * sc0;
        sc1 = sc1 > 0.f ? sc1 : NEG_SLOPE * sc1;
        sc2 = sc2 > 0.f ? sc2 : NEG_SLOPE * sc2;
        sc3 = sc3 > 0.f ? sc3 : NEG_SLOPE * sc3;
        float w0 = __expf(sc0 - m), w1 = __expf(sc1 - m);
        float w2 = __expf(sc2 - m), w3 = __expf(sc3 - m);
        den += w0 + w1 + w2 + w3;
        acc += w0 * bf2f(f0) + w1 * bf2f(f1) + w2 * bf2f(f2) + w3 * bf2f(f3);
    }
    for (; k < end; k++) {
        int s = csr_src[k];
        float sc = el[s] + erd;
        sc = sc > 0.f ? sc : NEG_SLOPE * sc;
        float w = __expf(sc - m);
        den += w;
        acc += w * bf2f(feat[(size_t)s * 64 + lane]);
    }
    float inv = (den > 0.f) ? 1.f / den : 0.f;
    float v = fmaxf(acc * inv + bias[lane], 0.f);
    go[(size_t)node * 64 + lane] = v;
    float sum = v;
    #pragma unroll
    for (int off = 1; off < 64; off <<= 1) sum += __shfl_xor(sum, off);
    if (lane == 0) emb[node] = sum;
}

extern "C" void kernel_launch(void* const* d_in, const int* in_sizes, int n_in,
                              void* d_out, int out_size, void* d_ws, size_t ws_size,
                              hipStream_t stream) {
    const float* x   = (const float*)d_in[0];
    const int*   src = (const int*)d_in[1];
    const int*   dst = (const int*)d_in[2];
    const float* W1  = (const float*)d_in[3];
    const float* al1 = (const float*)d_in[4];
    const float* ar1 = (const float*)d_in[5];
    const float* b1  = (const float*)d_in[6];
    const float* W2  = (const float*)d_in[7];
    const float* al2 = (const float*)d_in[8];
    const float* ar2 = (const float*)d_in[9];
    const float* b2  = (const float*)d_in[10];
    const int N = in_sizes[0] / 128;
    const int E = in_sizes[1];
    const int NB = (N + 255) / 256;

    char* base = (char*)d_ws;
    size_t off = 0;
    auto alloc = [&](size_t bytes) {
        off = (off + 255) & ~(size_t)255;
        void* p = base + off;
        off += bytes;
        return p;
    };
    unsigned short* feat1 = (unsigned short*)alloc((size_t)N * 256 * 2);
    unsigned short* feat2 = (unsigned short*)alloc((size_t)N * 64 * 2);
    float* el1   = (float*)alloc((size_t)N * 4 * 4);
    float* er1   = (float*)alloc((size_t)N * 4 * 4);
    float* el2   = (float*)alloc((size_t)N * 4);
    float* er2   = (float*)alloc((size_t)N * 4);
    int* icounts = (int*)alloc((size_t)N * 4);
    int* icursor = (int*)alloc((size_t)N * 4);
    int* ibsum   = (int*)alloc((size_t)(NB + 1) * 4);
    int* irowp   = (int*)alloc((size_t)(N + 1) * 4);
    int* icsrs   = (int*)alloc((size_t)E * 4);
    unsigned short* xh   = (unsigned short*)alloc((size_t)N * 128 * 2);
    unsigned short* xl   = (unsigned short*)alloc((size_t)N * 128 * 2);
    unsigned short* w1th = (unsigned short*)alloc((size_t)128 * 256 * 2);
    unsigned short* w1tl = (unsigned short*)alloc((size_t)128 * 256 * 2);
    unsigned short* hh   = (unsigned short*)alloc((size_t)N * 256 * 2);
    unsigned short* hl   = (unsigned short*)alloc((size_t)N * 256 * 2);
    unsigned short* w2th = (unsigned short*)alloc((size_t)256 * 64 * 2);
    unsigned short* w2tl = (unsigned short*)alloc((size_t)256 * 64 * 2);
    (void)ws_size;

    // --- CSR build (dst-indexed) ---
    zero_kernel<<<128, 256, 0, stream>>>(icounts, N);
    zero_kernel<<<128, 256, 0, stream>>>(icursor, N);
    hist_kernel<<<(E + 255) / 256, 256, 0, stream>>>(dst, icounts, E);
    bsum_kernel<<<NB, 256, 0, stream>>>(icounts, ibsum, N);
    bscan_kernel<<<1, 256, 0, stream>>>(ibsum, NB, irowp, N, E);
    rowptr_kernel<<<NB, 256, 0, stream>>>(icounts, ibsum, irowp, N);
    fill_kernel<<<(E + 255) / 256, 256, 0, stream>>>(src, dst, irowp, icursor, icsrs, E);

    // --- input/weight splits ---
    split_hl<<<(N * 128 / 4 + 255) / 256, 256, 0, stream>>>(x, xh, xl, N * 128 / 4);
    splitT_hl<<<(128 * 256 + 255) / 256, 256, 0, stream>>>(W1, w1th, w1tl, 128, 256);
    splitT_hl<<<(256 * 64 + 255) / 256, 256, 0, stream>>>(W2, w2th, w2tl, 256, 64);

    // --- layer 1 ---
    {
        dim3 g((N + 63) / 64, 256 / 64);
        gemm_mfma<<<g, 256, 0, stream>>>(xh, xl, w1th, w1tl, feat1, N, 256, 128);
    }
    elr1_kernel<<<(N + 3) / 4, 256, 0, stream>>>(feat1, al1, ar1, el1, er1, N);
    gat1_node<<<(N + 3) / 4, 256, 0, stream>>>(feat1, el1, er1, irowp, icsrs, b1, hh, hl, N);

    // --- layer 2 ---
    {
        dim3 g((N + 63) / 64, 1);
        gemm_mfma<<<g, 256, 0, stream>>>(hh, hl, w2th, w2tl, feat2, N, 64, 256);
    }
    elr2_kernel<<<(N + 3) / 4, 256, 0, stream>>>(feat2, al2, ar2, el2, er2, N);
    gat2_node<<<(N + 3) / 4, 256, 0, stream>>>(feat2, el2, er2, irowp, icsrs, b2,
                                               (float*)d_out, (float*)d_out + N, N);
}

// Round 5
// 264.444 us; speedup vs baseline: 14.8383x; 1.3519x over previous
//
#include <hip/hip_runtime.h>
#include <hip/hip_bf16.h>

#define NEG_SLOPE 0.2f

typedef __attribute__((ext_vector_type(8))) short short8v;
typedef __attribute__((ext_vector_type(4))) float f32x4;

// ---------- bf16 round-to-nearest helpers ----------
__device__ __forceinline__ unsigned short f2bf(float f) {
    unsigned u = __float_as_uint(f);
    unsigned r = (u + 0x7FFFu + ((u >> 16) & 1u)) >> 16;
    return (unsigned short)r;
}
__device__ __forceinline__ float bf2f(unsigned short h) {
    return __uint_as_float((unsigned)h << 16);
}

// ---------- zero ints ----------
__global__ __launch_bounds__(256) void zero_kernel(int* p, int n) {
    int i = blockIdx.x * 256 + threadIdx.x;
    int stride = gridDim.x * 256;
    for (int k = i; k < n; k += stride) p[k] = 0;
}

// ---------- CSR build ----------
__global__ __launch_bounds__(256) void hist_kernel(const int* __restrict__ dst,
                                                   int* __restrict__ counts, int E) {
    int e = blockIdx.x * 256 + threadIdx.x;
    if (e < E) atomicAdd(counts + dst[e], 1);
}

__global__ __launch_bounds__(256) void bsum_kernel(const int* __restrict__ counts,
                                                   int* __restrict__ bsum, int N) {
    __shared__ int sh[256];
    int i = blockIdx.x * 256 + threadIdx.x;
    int v = (i < N) ? counts[i] : 0;
    sh[threadIdx.x] = v;
    __syncthreads();
    for (int off = 128; off > 0; off >>= 1) {
        if (threadIdx.x < off) sh[threadIdx.x] += sh[threadIdx.x + off];
        __syncthreads();
    }
    if (threadIdx.x == 0) bsum[blockIdx.x] = sh[0];
}

__global__ __launch_bounds__(256) void bscan_kernel(int* __restrict__ bsum, int nb,
                                                    int* __restrict__ rowptr, int N, int E) {
    __shared__ int sh[256];
    int tid = threadIdx.x;
    int carry = 0;
    for (int base = 0; base < nb; base += 256) {
        int i = base + tid;
        int v = (i < nb) ? bsum[i] : 0;
        sh[tid] = v;
        __syncthreads();
        for (int off = 1; off < 256; off <<= 1) {
            int t = (tid >= off) ? sh[tid - off] : 0;
            __syncthreads();
            sh[tid] += t;
            __syncthreads();
        }
        if (i < nb) bsum[i] = carry + sh[tid] - v;  // exclusive
        int tot = sh[255];
        __syncthreads();
        carry += tot;
    }
    if (tid == 0) rowptr[N] = E;
}

__global__ __launch_bounds__(256) void rowptr_kernel(const int* __restrict__ counts,
                                                     const int* __restrict__ bsum,
                                                     int* __restrict__ rowptr, int N) {
    __shared__ int sh[256];
    int i = blockIdx.x * 256 + threadIdx.x;
    int tid = threadIdx.x;
    int v = (i < N) ? counts[i] : 0;
    sh[tid] = v;
    __syncthreads();
    for (int off = 1; off < 256; off <<= 1) {
        int t = (tid >= off) ? sh[tid - off] : 0;
        __syncthreads();
        sh[tid] += t;
        __syncthreads();
    }
    if (i < N) rowptr[i] = bsum[blockIdx.x] + sh[tid] - v;  // exclusive
}

__global__ __launch_bounds__(256) void fill_kernel(const int* __restrict__ src,
                                                   const int* __restrict__ dst,
                                                   const int* __restrict__ rowptr,
                                                   int* __restrict__ cursor,
                                                   int* __restrict__ csr_src, int E) {
    int e = blockIdx.x * 256 + threadIdx.x;
    if (e >= E) return;
    int d = dst[e];
    int pos = atomicAdd(cursor + d, 1);
    csr_src[rowptr[d] + pos] = src[e];
}

// ---------- split + transpose W[K,Nn] -> Wt hi/lo [Nn,K] ----------
__global__ __launch_bounds__(256) void splitT_hl(const float* __restrict__ W,
                                                 unsigned short* __restrict__ hiT,
                                                 unsigned short* __restrict__ loT,
                                                 int K, int Nn) {
    int tid = blockIdx.x * 256 + threadIdx.x;
    if (tid >= K * Nn) return;
    int k = tid / Nn, n = tid % Nn;
    float f = W[tid];
    unsigned short h = f2bf(f);
    hiT[(size_t)n * K + k] = h;
    loT[(size_t)n * K + k] = f2bf(f - bf2f(h));
}

// ---------- MFMA GEMM with fused el/er epilogue ----------
// C[M,Nn](bf16) = A[M,K] @ Wt[Nn,K]^T  via bf16 hi/lo x3.
// BM=64, BN=64, BK=128; 256 thr = 4 waves; wave w -> rows w*16..+15.
// A block's 64 cols == one head (blockIdx.y); epilogue computes
// el[r*H+head] = sum_c feat*attn_l, er likewise (fp32-accurate).
template<bool A_FP32>
__global__ __launch_bounds__(256) void gemm_mfma(const void* __restrict__ A_any,
                                                 const unsigned short* __restrict__ Al_g,
                                                 const unsigned short* __restrict__ Bh_g,
                                                 const unsigned short* __restrict__ Bl_g,
                                                 unsigned short* __restrict__ C,
                                                 const float* __restrict__ attn_l,
                                                 const float* __restrict__ attn_r,
                                                 float* __restrict__ el,
                                                 float* __restrict__ er,
                                                 int H, int M, int Nn, int K) {
    __shared__ unsigned short Ah[64][136], Al[64][136], Bh[64][136], Bl[64][136];
    int tid = threadIdx.x;
    int row0 = blockIdx.x * 64;
    int col0 = blockIdx.y * 64;
    int wv = tid >> 6;
    int lane = tid & 63;
    int l15 = lane & 15;
    int kgrp = (lane >> 4) * 8;

    f32x4 acc[4] = {{0.f,0.f,0.f,0.f},{0.f,0.f,0.f,0.f},{0.f,0.f,0.f,0.f},{0.f,0.f,0.f,0.f}};

    for (int kc = 0; kc < K; kc += 128) {
        __syncthreads();
        #pragma unroll
        for (int p = 0; p < 4; p++) {
            int idx = (p * 256 + tid) * 8;
            int r = idx >> 7;          // /128
            int c = idx & 127;
            int gr = row0 + r;
            if (A_FP32) {
                const float* A = (const float*)A_any;
                float4 v0 = {0,0,0,0}, v1 = {0,0,0,0};
                if (gr < M) {
                    v0 = *(const float4*)(A + (size_t)gr * K + kc + c);
                    v1 = *(const float4*)(A + (size_t)gr * K + kc + c + 4);
                }
                ushort4 h0, l0, h1, l1;
                h0.x = f2bf(v0.x); l0.x = f2bf(v0.x - bf2f(h0.x));
                h0.y = f2bf(v0.y); l0.y = f2bf(v0.y - bf2f(h0.y));
                h0.z = f2bf(v0.z); l0.z = f2bf(v0.z - bf2f(h0.z));
                h0.w = f2bf(v0.w); l0.w = f2bf(v0.w - bf2f(h0.w));
                h1.x = f2bf(v1.x); l1.x = f2bf(v1.x - bf2f(h1.x));
                h1.y = f2bf(v1.y); l1.y = f2bf(v1.y - bf2f(h1.y));
                h1.z = f2bf(v1.z); l1.z = f2bf(v1.z - bf2f(h1.z));
                h1.w = f2bf(v1.w); l1.w = f2bf(v1.w - bf2f(h1.w));
                *(ushort4*)&Ah[r][c]     = h0;
                *(ushort4*)&Ah[r][c + 4] = h1;
                *(ushort4*)&Al[r][c]     = l0;
                *(ushort4*)&Al[r][c + 4] = l1;
            } else {
                const unsigned short* Ah_g = (const unsigned short*)A_any;
                uint4 vh = {0,0,0,0}, vl = {0,0,0,0};
                if (gr < M) {
                    vh = *(const uint4*)(Ah_g + (size_t)gr * K + kc + c);
                    vl = *(const uint4*)(Al_g + (size_t)gr * K + kc + c);
                }
                *(uint4*)&Ah[r][c] = vh;
                *(uint4*)&Al[r][c] = vl;
            }
            // B tile: rows are output cols (Wt layout [Nn][K])
            uint4 wh = *(const uint4*)(Bh_g + (size_t)(col0 + r) * K + kc + c);
            uint4 wl = *(const uint4*)(Bl_g + (size_t)(col0 + r) * K + kc + c);
            *(uint4*)&Bh[r][c] = wh;
            *(uint4*)&Bl[r][c] = wl;
        }
        __syncthreads();
        #pragma unroll
        for (int kk = 0; kk < 4; kk++) {
            int kc0 = kk * 32 + kgrp;
            short8v ah = *(short8v*)&Ah[wv * 16 + l15][kc0];
            short8v al = *(short8v*)&Al[wv * 16 + l15][kc0];
            #pragma unroll
            for (int c = 0; c < 4; c++) {
                short8v bh = *(short8v*)&Bh[c * 16 + l15][kc0];
                short8v bl = *(short8v*)&Bl[c * 16 + l15][kc0];
                acc[c] = __builtin_amdgcn_mfma_f32_16x16x32_bf16(ah, bh, acc[c], 0, 0, 0);
                acc[c] = __builtin_amdgcn_mfma_f32_16x16x32_bf16(ah, bl, acc[c], 0, 0, 0);
                acc[c] = __builtin_amdgcn_mfma_f32_16x16x32_bf16(al, bh, acc[c], 0, 0, 0);
            }
        }
    }
    // C/D layout: col = lane&15, row = (lane>>4)*4 + j
    float elp[4] = {0.f, 0.f, 0.f, 0.f};
    float erp[4] = {0.f, 0.f, 0.f, 0.f};
    const float* alh = attn_l + blockIdx.y * 64;
    const float* arh = attn_r + blockIdx.y * 64;
    #pragma unroll
    for (int c = 0; c < 4; c++) {
        float av = alh[c * 16 + l15];
        float rv = arh[c * 16 + l15];
        #pragma unroll
        for (int j = 0; j < 4; j++) {
            int r = row0 + wv * 16 + (lane >> 4) * 4 + j;
            if (r < M) C[(size_t)r * Nn + col0 + c * 16 + l15] = f2bf(acc[c][j]);
            elp[j] += acc[c][j] * av;
            erp[j] += acc[c][j] * rv;
        }
    }
    #pragma unroll
    for (int j = 0; j < 4; j++) {
        #pragma unroll
        for (int off = 1; off < 16; off <<= 1) {
            elp[j] += __shfl_xor(elp[j], off);
            erp[j] += __shfl_xor(erp[j], off);
        }
    }
    if (l15 == 0) {
        #pragma unroll
        for (int j = 0; j < 4; j++) {
            int r = row0 + wv * 16 + (lane >> 4) * 4 + j;
            if (r < M) {
                el[(size_t)r * H + blockIdx.y] = elp[j];
                er[(size_t)r * H + blockIdx.y] = erp[j];
            }
        }
    }
}

// ---------- layer1 fused per-node, single-pass softmax (no max subtraction) ----------
// one wave per node; bf16 feat gather; out as bf16 hi/lo for GEMM2
__global__ __launch_bounds__(256) void gat1_node(const unsigned short* __restrict__ feat,
                                                 const float* __restrict__ el,
                                                 const float* __restrict__ er,
                                                 const int* __restrict__ rowptr,
                                                 const int* __restrict__ csr_src,
                                                 const float* __restrict__ bias,
                                                 unsigned short* __restrict__ out_h,
                                                 unsigned short* __restrict__ out_l, int N) {
    int node = (blockIdx.x * 256 + threadIdx.x) >> 6;
    int lane = threadIdx.x & 63;
    if (node >= N) return;
    int h = lane >> 4;
    int beg = rowptr[node], end = rowptr[node + 1];
    float erd = er[(size_t)node * 4 + h];
    float den = 0.f;
    float4 acc = {0.f, 0.f, 0.f, 0.f};
    int k = beg;
    for (; k + 1 < end; k += 2) {
        int s0 = csr_src[k], s1 = csr_src[k + 1];
        float sc0 = el[(size_t)s0 * 4 + h] + erd;
        float sc1 = el[(size_t)s1 * 4 + h] + erd;
        ushort4 f0 = *(const ushort4*)(feat + (size_t)s0 * 256 + lane * 4);
        ushort4 f1 = *(const ushort4*)(feat + (size_t)s1 * 256 + lane * 4);
        sc0 = sc0 > 0.f ? sc0 : NEG_SLOPE * sc0;
        sc1 = sc1 > 0.f ? sc1 : NEG_SLOPE * sc1;
        float w0 = __expf(sc0), w1 = __expf(sc1);
        den += w0 + w1;
        acc.x += w0 * bf2f(f0.x) + w1 * bf2f(f1.x);
        acc.y += w0 * bf2f(f0.y) + w1 * bf2f(f1.y);
        acc.z += w0 * bf2f(f0.z) + w1 * bf2f(f1.z);
        acc.w += w0 * bf2f(f0.w) + w1 * bf2f(f1.w);
    }
    if (k < end) {
        int s = csr_src[k];
        float sc = el[(size_t)s * 4 + h] + erd;
        sc = sc > 0.f ? sc : NEG_SLOPE * sc;
        float w = __expf(sc);
        ushort4 f = *(const ushort4*)(feat + (size_t)s * 256 + lane * 4);
        den += w;
        acc.x += w * bf2f(f.x);
        acc.y += w * bf2f(f.y);
        acc.z += w * bf2f(f.z);
        acc.w += w * bf2f(f.w);
    }
    float inv = (den > 0.f) ? 1.f / den : 0.f;
    float4 b = *(const float4*)(bias + lane * 4);
    float4 o;
    o.x = fmaxf(acc.x * inv + b.x, 0.f);
    o.y = fmaxf(acc.y * inv + b.y, 0.f);
    o.z = fmaxf(acc.z * inv + b.z, 0.f);
    o.w = fmaxf(acc.w * inv + b.w, 0.f);
    ushort4 oh, ol;
    oh.x = f2bf(o.x); ol.x = f2bf(o.x - bf2f(oh.x));
    oh.y = f2bf(o.y); ol.y = f2bf(o.y - bf2f(oh.y));
    oh.z = f2bf(o.z); ol.z = f2bf(o.z - bf2f(oh.z));
    oh.w = f2bf(o.w); ol.w = f2bf(o.w - bf2f(oh.w));
    *(ushort4*)(out_h + (size_t)node * 256 + lane * 4) = oh;
    *(ushort4*)(out_l + (size_t)node * 256 + lane * 4) = ol;
}

// ---------- layer2 fused per-node, single-pass + bias + relu + row-sum ----------
__global__ __launch_bounds__(256) void gat2_node(const unsigned short* __restrict__ feat,
                                                 const float* __restrict__ el,
                                                 const float* __restrict__ er,
                                                 const int* __restrict__ rowptr,
                                                 const int* __restrict__ csr_src,
                                                 const float* __restrict__ bias,
                                                 float* __restrict__ emb,
                                                 float* __restrict__ go, int N) {
    int node = (blockIdx.x * 256 + threadIdx.x) >> 6;
    int lane = threadIdx.x & 63;
    if (node >= N) return;
    int beg = rowptr[node], end = rowptr[node + 1];
    float erd = er[node];
    float den = 0.f, acc = 0.f;
    int k = beg;
    for (; k + 3 < end; k += 4) {
        int s0 = csr_src[k], s1 = csr_src[k + 1], s2 = csr_src[k + 2], s3 = csr_src[k + 3];
        float sc0 = el[s0] + erd, sc1 = el[s1] + erd, sc2 = el[s2] + erd, sc3 = el[s3] + erd;
        unsigned short f0 = feat[(size_t)s0 * 64 + lane];
        unsigned short f1 = feat[(size_t)s1 * 64 + lane];
        unsigned short f2 = feat[(size_t)s2 * 64 + lane];
        unsigned short f3 = feat[(size_t)s3 * 64 + lane];
        sc0 = sc0 > 0.f ? sc0 : NEG_SLOPE * sc0;
        sc1 = sc1 > 0.f ? sc1 : NEG_SLOPE * sc1;
        sc2 = sc2 > 0.f ? sc2 : NEG_SLOPE * sc2;
        sc3 = sc3 > 0.f ? sc3 : NEG_SLOPE * sc3;
        float w0 = __expf(sc0), w1 = __expf(sc1);
        float w2 = __expf(sc2), w3 = __expf(sc3);
        den += w0 + w1 + w2 + w3;
        acc += w0 * bf2f(f0) + w1 * bf2f(f1) + w2 * bf2f(f2) + w3 * bf2f(f3);
    }
    for (; k < end; k++) {
        int s = csr_src[k];
        float sc = el[s] + erd;
        sc = sc > 0.f ? sc : NEG_SLOPE * sc;
        float w = __expf(sc);
        den += w;
        acc += w * bf2f(feat[(size_t)s * 64 + lane]);
    }
    float inv = (den > 0.f) ? 1.f / den : 0.f;
    float v = fmaxf(acc * inv + bias[lane], 0.f);
    go[(size_t)node * 64 + lane] = v;
    float sum = v;
    #pragma unroll
    for (int off = 1; off < 64; off <<= 1) sum += __shfl_xor(sum, off);
    if (lane == 0) emb[node] = sum;
}

extern "C" void kernel_launch(void* const* d_in, const int* in_sizes, int n_in,
                              void* d_out, int out_size, void* d_ws, size_t ws_size,
                              hipStream_t stream) {
    const float* x   = (const float*)d_in[0];
    const int*   src = (const int*)d_in[1];
    const int*   dst = (const int*)d_in[2];
    const float* W1  = (const float*)d_in[3];
    const float* al1 = (const float*)d_in[4];
    const float* ar1 = (const float*)d_in[5];
    const float* b1  = (const float*)d_in[6];
    const float* W2  = (const float*)d_in[7];
    const float* al2 = (const float*)d_in[8];
    const float* ar2 = (const float*)d_in[9];
    const float* b2  = (const float*)d_in[10];
    const int N = in_sizes[0] / 128;
    const int E = in_sizes[1];
    const int NB = (N + 255) / 256;

    char* base = (char*)d_ws;
    size_t off = 0;
    auto alloc = [&](size_t bytes) {
        off = (off + 255) & ~(size_t)255;
        void* p = base + off;
        off += bytes;
        return p;
    };
    unsigned short* feat1 = (unsigned short*)alloc((size_t)N * 256 * 2);
    unsigned short* feat2 = (unsigned short*)alloc((size_t)N * 64 * 2);
    float* el1   = (float*)alloc((size_t)N * 4 * 4);
    float* er1   = (float*)alloc((size_t)N * 4 * 4);
    float* el2   = (float*)alloc((size_t)N * 4);
    float* er2   = (float*)alloc((size_t)N * 4);
    int* icounts = (int*)alloc((size_t)N * 4);
    int* icursor = (int*)alloc((size_t)N * 4);
    int* ibsum   = (int*)alloc((size_t)(NB + 1) * 4);
    int* irowp   = (int*)alloc((size_t)(N + 1) * 4);
    int* icsrs   = (int*)alloc((size_t)E * 4);
    unsigned short* w1th = (unsigned short*)alloc((size_t)128 * 256 * 2);
    unsigned short* w1tl = (unsigned short*)alloc((size_t)128 * 256 * 2);
    unsigned short* hh   = (unsigned short*)alloc((size_t)N * 256 * 2);
    unsigned short* hl   = (unsigned short*)alloc((size_t)N * 256 * 2);
    unsigned short* w2th = (unsigned short*)alloc((size_t)256 * 64 * 2);
    unsigned short* w2tl = (unsigned short*)alloc((size_t)256 * 64 * 2);
    (void)ws_size;

    // --- CSR build (dst-indexed) ---
    zero_kernel<<<128, 256, 0, stream>>>(icounts, N);
    zero_kernel<<<128, 256, 0, stream>>>(icursor, N);
    hist_kernel<<<(E + 255) / 256, 256, 0, stream>>>(dst, icounts, E);
    bsum_kernel<<<NB, 256, 0, stream>>>(icounts, ibsum, N);
    bscan_kernel<<<1, 256, 0, stream>>>(ibsum, NB, irowp, N, E);
    rowptr_kernel<<<NB, 256, 0, stream>>>(icounts, ibsum, irowp, N);
    fill_kernel<<<(E + 255) / 256, 256, 0, stream>>>(src, dst, irowp, icursor, icsrs, E);

    // --- weight splits ---
    splitT_hl<<<(128 * 256 + 255) / 256, 256, 0, stream>>>(W1, w1th, w1tl, 128, 256);
    splitT_hl<<<(256 * 64 + 255) / 256, 256, 0, stream>>>(W2, w2th, w2tl, 256, 64);

    // --- layer 1 ---
    {
        dim3 g((N + 63) / 64, 256 / 64);
        gemm_mfma<true><<<g, 256, 0, stream>>>(x, nullptr, w1th, w1tl, feat1,
                                               al1, ar1, el1, er1, 4, N, 256, 128);
    }
    gat1_node<<<(N + 3) / 4, 256, 0, stream>>>(feat1, el1, er1, irowp, icsrs, b1, hh, hl, N);

    // --- layer 2 ---
    {
        dim3 g((N + 63) / 64, 1);
        gemm_mfma<false><<<g, 256, 0, stream>>>(hh, hl, w2th, w2tl, feat2,
                                                al2, ar2, el2, er2, 1, N, 64, 256);
    }
    gat2_node<<<(N + 3) / 4, 256, 0, stream>>>(feat2, el2, er2, irowp, icsrs, b2,
                                               (float*)d_out, (float*)d_out + N, N);
}

// Round 6
// 259.779 us; speedup vs baseline: 15.1048x; 1.0180x over previous
//
#include <hip/hip_runtime.h>
#include <hip/hip_bf16.h>

#define NEG_SLOPE 0.2f

typedef __attribute__((ext_vector_type(8))) short short8v;
typedef __attribute__((ext_vector_type(4))) float f32x4;

// ---------- bf16 round-to-nearest helpers ----------
__device__ __forceinline__ unsigned short f2bf(float f) {
    unsigned u = __float_as_uint(f);
    unsigned r = (u + 0x7FFFu + ((u >> 16) & 1u)) >> 16;
    return (unsigned short)r;
}
__device__ __forceinline__ float bf2f(unsigned short h) {
    return __uint_as_float((unsigned)h << 16);
}

// ---------- zero ints ----------
__global__ __launch_bounds__(256) void zero_kernel(int* p, int n) {
    int i = blockIdx.x * 256 + threadIdx.x;
    int stride = gridDim.x * 256;
    for (int k = i; k < n; k += stride) p[k] = 0;
}

// ---------- CSR build ----------
__global__ __launch_bounds__(256) void hist_kernel(const int* __restrict__ dst,
                                                   int* __restrict__ counts, int E) {
    int e = blockIdx.x * 256 + threadIdx.x;
    if (e < E) atomicAdd(counts + dst[e], 1);
}

__global__ __launch_bounds__(256) void bsum_kernel(const int* __restrict__ counts,
                                                   int* __restrict__ bsum, int N) {
    __shared__ int sh[256];
    int i = blockIdx.x * 256 + threadIdx.x;
    int v = (i < N) ? counts[i] : 0;
    sh[threadIdx.x] = v;
    __syncthreads();
    for (int off = 128; off > 0; off >>= 1) {
        if (threadIdx.x < off) sh[threadIdx.x] += sh[threadIdx.x + off];
        __syncthreads();
    }
    if (threadIdx.x == 0) bsum[blockIdx.x] = sh[0];
}

__global__ __launch_bounds__(256) void bscan_kernel(int* __restrict__ bsum, int nb,
                                                    int* __restrict__ rowptr, int N, int E) {
    __shared__ int sh[256];
    int tid = threadIdx.x;
    int carry = 0;
    for (int base = 0; base < nb; base += 256) {
        int i = base + tid;
        int v = (i < nb) ? bsum[i] : 0;
        sh[tid] = v;
        __syncthreads();
        for (int off = 1; off < 256; off <<= 1) {
            int t = (tid >= off) ? sh[tid - off] : 0;
            __syncthreads();
            sh[tid] += t;
            __syncthreads();
        }
        if (i < nb) bsum[i] = carry + sh[tid] - v;  // exclusive
        int tot = sh[255];
        __syncthreads();
        carry += tot;
    }
    if (tid == 0) rowptr[N] = E;
}

__global__ __launch_bounds__(256) void rowptr_kernel(const int* __restrict__ counts,
                                                     const int* __restrict__ bsum,
                                                     int* __restrict__ rowptr, int N) {
    __shared__ int sh[256];
    int i = blockIdx.x * 256 + threadIdx.x;
    int tid = threadIdx.x;
    int v = (i < N) ? counts[i] : 0;
    sh[tid] = v;
    __syncthreads();
    for (int off = 1; off < 256; off <<= 1) {
        int t = (tid >= off) ? sh[tid - off] : 0;
        __syncthreads();
        sh[tid] += t;
        __syncthreads();
    }
    if (i < N) rowptr[i] = bsum[blockIdx.x] + sh[tid] - v;  // exclusive
}

__global__ __launch_bounds__(256) void fill_kernel(const int* __restrict__ src,
                                                   const int* __restrict__ dst,
                                                   const int* __restrict__ rowptr,
                                                   int* __restrict__ cursor,
                                                   int* __restrict__ csr_src, int E) {
    int e = blockIdx.x * 256 + threadIdx.x;
    if (e >= E) return;
    int d = dst[e];
    int pos = atomicAdd(cursor + d, 1);
    csr_src[rowptr[d] + pos] = src[e];
}

// ---------- split + transpose BOTH weights in one launch ----------
// W1[128,256] -> w1t hi/lo [256,128]; W2[256,64] -> w2t hi/lo [64,256]
__global__ __launch_bounds__(256) void splitT_both(const float* __restrict__ W1,
                                                   unsigned short* __restrict__ h1,
                                                   unsigned short* __restrict__ l1,
                                                   const float* __restrict__ W2,
                                                   unsigned short* __restrict__ h2,
                                                   unsigned short* __restrict__ l2) {
    int tid = blockIdx.x * 256 + threadIdx.x;
    if (tid < 128 * 256) {
        int k = tid >> 8, n = tid & 255;
        float f = W1[tid];
        unsigned short h = f2bf(f);
        h1[n * 128 + k] = h;
        l1[n * 128 + k] = f2bf(f - bf2f(h));
    } else {
        int t = tid - 128 * 256;
        if (t < 256 * 64) {
            int k = t >> 6, n = t & 63;
            float f = W2[t];
            unsigned short h = f2bf(f);
            h2[n * 256 + k] = h;
            l2[n * 256 + k] = f2bf(f - bf2f(h));
        }
    }
}

// ---------- MFMA GEMM with fused el/er epilogue ----------
// C[M,Nn](bf16) = A[M,K] @ Wt[Nn,K]^T  via bf16 hi/lo x3.
// BM=64, BN=64, BK=128; 256 thr = 4 waves; wave w -> rows w*16..+15.
// A block's 64 cols == one head (blockIdx.y); epilogue computes
// el[r*H+head] = sum_c feat*attn_l, er likewise (fp32-accurate).
template<bool A_FP32>
__global__ __launch_bounds__(256) void gemm_mfma(const void* __restrict__ A_any,
                                                 const unsigned short* __restrict__ Al_g,
                                                 const unsigned short* __restrict__ Bh_g,
                                                 const unsigned short* __restrict__ Bl_g,
                                                 unsigned short* __restrict__ C,
                                                 const float* __restrict__ attn_l,
                                                 const float* __restrict__ attn_r,
                                                 float* __restrict__ el,
                                                 float* __restrict__ er,
                                                 int H, int M, int Nn, int K) {
    __shared__ unsigned short Ah[64][136], Al[64][136], Bh[64][136], Bl[64][136];
    int tid = threadIdx.x;
    int row0 = blockIdx.x * 64;
    int col0 = blockIdx.y * 64;
    int wv = tid >> 6;
    int lane = tid & 63;
    int l15 = lane & 15;
    int kgrp = (lane >> 4) * 8;

    f32x4 acc[4] = {{0.f,0.f,0.f,0.f},{0.f,0.f,0.f,0.f},{0.f,0.f,0.f,0.f},{0.f,0.f,0.f,0.f}};

    for (int kc = 0; kc < K; kc += 128) {
        __syncthreads();
        #pragma unroll
        for (int p = 0; p < 4; p++) {
            int idx = (p * 256 + tid) * 8;
            int r = idx >> 7;          // /128
            int c = idx & 127;
            int gr = row0 + r;
            if (A_FP32) {
                const float* A = (const float*)A_any;
                float4 v0 = {0,0,0,0}, v1 = {0,0,0,0};
                if (gr < M) {
                    v0 = *(const float4*)(A + (size_t)gr * K + kc + c);
                    v1 = *(const float4*)(A + (size_t)gr * K + kc + c + 4);
                }
                ushort4 h0, l0, h1, l1;
                h0.x = f2bf(v0.x); l0.x = f2bf(v0.x - bf2f(h0.x));
                h0.y = f2bf(v0.y); l0.y = f2bf(v0.y - bf2f(h0.y));
                h0.z = f2bf(v0.z); l0.z = f2bf(v0.z - bf2f(h0.z));
                h0.w = f2bf(v0.w); l0.w = f2bf(v0.w - bf2f(h0.w));
                h1.x = f2bf(v1.x); l1.x = f2bf(v1.x - bf2f(h1.x));
                h1.y = f2bf(v1.y); l1.y = f2bf(v1.y - bf2f(h1.y));
                h1.z = f2bf(v1.z); l1.z = f2bf(v1.z - bf2f(h1.z));
                h1.w = f2bf(v1.w); l1.w = f2bf(v1.w - bf2f(h1.w));
                *(ushort4*)&Ah[r][c]     = h0;
                *(ushort4*)&Ah[r][c + 4] = h1;
                *(ushort4*)&Al[r][c]     = l0;
                *(ushort4*)&Al[r][c + 4] = l1;
            } else {
                const unsigned short* Ah_g = (const unsigned short*)A_any;
                uint4 vh = {0,0,0,0}, vl = {0,0,0,0};
                if (gr < M) {
                    vh = *(const uint4*)(Ah_g + (size_t)gr * K + kc + c);
                    vl = *(const uint4*)(Al_g + (size_t)gr * K + kc + c);
                }
                *(uint4*)&Ah[r][c] = vh;
                *(uint4*)&Al[r][c] = vl;
            }
            // B tile: rows are output cols (Wt layout [Nn][K])
            uint4 wh = *(const uint4*)(Bh_g + (size_t)(col0 + r) * K + kc + c);
            uint4 wl = *(const uint4*)(Bl_g + (size_t)(col0 + r) * K + kc + c);
            *(uint4*)&Bh[r][c] = wh;
            *(uint4*)&Bl[r][c] = wl;
        }
        __syncthreads();
        #pragma unroll
        for (int kk = 0; kk < 4; kk++) {
            int kc0 = kk * 32 + kgrp;
            short8v ah = *(short8v*)&Ah[wv * 16 + l15][kc0];
            short8v al = *(short8v*)&Al[wv * 16 + l15][kc0];
            #pragma unroll
            for (int c = 0; c < 4; c++) {
                short8v bh = *(short8v*)&Bh[c * 16 + l15][kc0];
                short8v bl = *(short8v*)&Bl[c * 16 + l15][kc0];
                acc[c] = __builtin_amdgcn_mfma_f32_16x16x32_bf16(ah, bh, acc[c], 0, 0, 0);
                acc[c] = __builtin_amdgcn_mfma_f32_16x16x32_bf16(ah, bl, acc[c], 0, 0, 0);
                acc[c] = __builtin_amdgcn_mfma_f32_16x16x32_bf16(al, bh, acc[c], 0, 0, 0);
            }
        }
    }
    // C/D layout: col = lane&15, row = (lane>>4)*4 + j
    float elp[4] = {0.f, 0.f, 0.f, 0.f};
    float erp[4] = {0.f, 0.f, 0.f, 0.f};
    const float* alh = attn_l + blockIdx.y * 64;
    const float* arh = attn_r + blockIdx.y * 64;
    #pragma unroll
    for (int c = 0; c < 4; c++) {
        float av = alh[c * 16 + l15];
        float rv = arh[c * 16 + l15];
        #pragma unroll
        for (int j = 0; j < 4; j++) {
            int r = row0 + wv * 16 + (lane >> 4) * 4 + j;
            if (r < M) C[(size_t)r * Nn + col0 + c * 16 + l15] = f2bf(acc[c][j]);
            elp[j] += acc[c][j] * av;
            erp[j] += acc[c][j] * rv;
        }
    }
    #pragma unroll
    for (int j = 0; j < 4; j++) {
        #pragma unroll
        for (int off = 1; off < 16; off <<= 1) {
            elp[j] += __shfl_xor(elp[j], off);
            erp[j] += __shfl_xor(erp[j], off);
        }
    }
    if (l15 == 0) {
        #pragma unroll
        for (int j = 0; j < 4; j++) {
            int r = row0 + wv * 16 + (lane >> 4) * 4 + j;
            if (r < M) {
                el[(size_t)r * H + blockIdx.y] = elp[j];
                er[(size_t)r * H + blockIdx.y] = erp[j];
            }
        }
    }
}

// ---------- layer1 fused per-node, single-pass softmax, unroll x4 ----------
// one wave per node; bf16 feat gather; out as bf16 hi/lo for GEMM2
__global__ __launch_bounds__(256) void gat1_node(const unsigned short* __restrict__ feat,
                                                 const float* __restrict__ el,
                                                 const float* __restrict__ er,
                                                 const int* __restrict__ rowptr,
                                                 const int* __restrict__ csr_src,
                                                 const float* __restrict__ bias,
                                                 unsigned short* __restrict__ out_h,
                                                 unsigned short* __restrict__ out_l, int N) {
    int node = (blockIdx.x * 256 + threadIdx.x) >> 6;
    int lane = threadIdx.x & 63;
    if (node >= N) return;
    int h = lane >> 4;
    int beg = rowptr[node], end = rowptr[node + 1];
    float erd = er[(size_t)node * 4 + h];
    float den = 0.f;
    float4 acc = {0.f, 0.f, 0.f, 0.f};
    int k = beg;
    for (; k + 3 < end; k += 4) {
        // issue ALL loads before any compute: 4 idx -> 4 el + 4 feat in flight
        int s0 = csr_src[k], s1 = csr_src[k + 1];
        int s2 = csr_src[k + 2], s3 = csr_src[k + 3];
        float e0 = el[(size_t)s0 * 4 + h];
        float e1 = el[(size_t)s1 * 4 + h];
        float e2 = el[(size_t)s2 * 4 + h];
        float e3 = el[(size_t)s3 * 4 + h];
        ushort4 f0 = *(const ushort4*)(feat + (size_t)s0 * 256 + lane * 4);
        ushort4 f1 = *(const ushort4*)(feat + (size_t)s1 * 256 + lane * 4);
        ushort4 f2 = *(const ushort4*)(feat + (size_t)s2 * 256 + lane * 4);
        ushort4 f3 = *(const ushort4*)(feat + (size_t)s3 * 256 + lane * 4);
        float sc0 = e0 + erd, sc1 = e1 + erd, sc2 = e2 + erd, sc3 = e3 + erd;
        sc0 = sc0 > 0.f ? sc0 : NEG_SLOPE * sc0;
        sc1 = sc1 > 0.f ? sc1 : NEG_SLOPE * sc1;
        sc2 = sc2 > 0.f ? sc2 : NEG_SLOPE * sc2;
        sc3 = sc3 > 0.f ? sc3 : NEG_SLOPE * sc3;
        float w0 = __expf(sc0), w1 = __expf(sc1);
        float w2 = __expf(sc2), w3 = __expf(sc3);
        den += (w0 + w1) + (w2 + w3);
        acc.x += w0 * bf2f(f0.x) + w1 * bf2f(f1.x) + w2 * bf2f(f2.x) + w3 * bf2f(f3.x);
        acc.y += w0 * bf2f(f0.y) + w1 * bf2f(f1.y) + w2 * bf2f(f2.y) + w3 * bf2f(f3.y);
        acc.z += w0 * bf2f(f0.z) + w1 * bf2f(f1.z) + w2 * bf2f(f2.z) + w3 * bf2f(f3.z);
        acc.w += w0 * bf2f(f0.w) + w1 * bf2f(f1.w) + w2 * bf2f(f2.w) + w3 * bf2f(f3.w);
    }
    for (; k < end; k++) {
        int s = csr_src[k];
        float sc = el[(size_t)s * 4 + h] + erd;
        sc = sc > 0.f ? sc : NEG_SLOPE * sc;
        float w = __expf(sc);
        ushort4 f = *(const ushort4*)(feat + (size_t)s * 256 + lane * 4);
        den += w;
        acc.x += w * bf2f(f.x);
        acc.y += w * bf2f(f.y);
        acc.z += w * bf2f(f.z);
        acc.w += w * bf2f(f.w);
    }
    float inv = (den > 0.f) ? 1.f / den : 0.f;
    float4 b = *(const float4*)(bias + lane * 4);
    float4 o;
    o.x = fmaxf(acc.x * inv + b.x, 0.f);
    o.y = fmaxf(acc.y * inv + b.y, 0.f);
    o.z = fmaxf(acc.z * inv + b.z, 0.f);
    o.w = fmaxf(acc.w * inv + b.w, 0.f);
    ushort4 oh, ol;
    oh.x = f2bf(o.x); ol.x = f2bf(o.x - bf2f(oh.x));
    oh.y = f2bf(o.y); ol.y = f2bf(o.y - bf2f(oh.y));
    oh.z = f2bf(o.z); ol.z = f2bf(o.z - bf2f(oh.z));
    oh.w = f2bf(o.w); ol.w = f2bf(o.w - bf2f(oh.w));
    *(ushort4*)(out_h + (size_t)node * 256 + lane * 4) = oh;
    *(ushort4*)(out_l + (size_t)node * 256 + lane * 4) = ol;
}

// ---------- layer2 fused per-node, single-pass + bias + relu + row-sum ----------
__global__ __launch_bounds__(256) void gat2_node(const unsigned short* __restrict__ feat,
                                                 const float* __restrict__ el,
                                                 const float* __restrict__ er,
                                                 const int* __restrict__ rowptr,
                                                 const int* __restrict__ csr_src,
                                                 const float* __restrict__ bias,
                                                 float* __restrict__ emb,
                                                 float* __restrict__ go, int N) {
    int node = (blockIdx.x * 256 + threadIdx.x) >> 6;
    int lane = threadIdx.x & 63;
    if (node >= N) return;
    int beg = rowptr[node], end = rowptr[node + 1];
    float erd = er[node];
    float den = 0.f, acc = 0.f;
    int k = beg;
    for (; k + 3 < end; k += 4) {
        int s0 = csr_src[k], s1 = csr_src[k + 1], s2 = csr_src[k + 2], s3 = csr_src[k + 3];
        float e0 = el[s0], e1 = el[s1], e2 = el[s2], e3 = el[s3];
        unsigned short f0 = feat[(size_t)s0 * 64 + lane];
        unsigned short f1 = feat[(size_t)s1 * 64 + lane];
        unsigned short f2 = feat[(size_t)s2 * 64 + lane];
        unsigned short f3 = feat[(size_t)s3 * 64 + lane];
        float sc0 = e0 + erd, sc1 = e1 + erd, sc2 = e2 + erd, sc3 = e3 + erd;
        sc0 = sc0 > 0.f ? sc0 : NEG_SLOPE * sc0;
        sc1 = sc1 > 0.f ? sc1 : NEG_SLOPE * sc1;
        sc2 = sc2 > 0.f ? sc2 : NEG_SLOPE * sc2;
        sc3 = sc3 > 0.f ? sc3 : NEG_SLOPE * sc3;
        float w0 = __expf(sc0), w1 = __expf(sc1);
        float w2 = __expf(sc2), w3 = __expf(sc3);
        den += (w0 + w1) + (w2 + w3);
        acc += w0 * bf2f(f0) + w1 * bf2f(f1) + w2 * bf2f(f2) + w3 * bf2f(f3);
    }
    for (; k < end; k++) {
        int s = csr_src[k];
        float sc = el[s] + erd;
        sc = sc > 0.f ? sc : NEG_SLOPE * sc;
        float w = __expf(sc);
        den += w;
        acc += w * bf2f(feat[(size_t)s * 64 + lane]);
    }
    float inv = (den > 0.f) ? 1.f / den : 0.f;
    float v = fmaxf(acc * inv + bias[lane], 0.f);
    go[(size_t)node * 64 + lane] = v;
    float sum = v;
    #pragma unroll
    for (int off = 1; off < 64; off <<= 1) sum += __shfl_xor(sum, off);
    if (lane == 0) emb[node] = sum;
}

extern "C" void kernel_launch(void* const* d_in, const int* in_sizes, int n_in,
                              void* d_out, int out_size, void* d_ws, size_t ws_size,
                              hipStream_t stream) {
    const float* x   = (const float*)d_in[0];
    const int*   src = (const int*)d_in[1];
    const int*   dst = (const int*)d_in[2];
    const float* W1  = (const float*)d_in[3];
    const float* al1 = (const float*)d_in[4];
    const float* ar1 = (const float*)d_in[5];
    const float* b1  = (const float*)d_in[6];
    const float* W2  = (const float*)d_in[7];
    const float* al2 = (const float*)d_in[8];
    const float* ar2 = (const float*)d_in[9];
    const float* b2  = (const float*)d_in[10];
    const int N = in_sizes[0] / 128;
    const int E = in_sizes[1];
    const int NB = (N + 255) / 256;

    char* base = (char*)d_ws;
    size_t off = 0;
    auto alloc = [&](size_t bytes) {
        off = (off + 255) & ~(size_t)255;
        void* p = base + off;
        off += bytes;
        return p;
    };
    unsigned short* feat1 = (unsigned short*)alloc((size_t)N * 256 * 2);
    unsigned short* feat2 = (unsigned short*)alloc((size_t)N * 64 * 2);
    float* el1   = (float*)alloc((size_t)N * 4 * 4);
    float* er1   = (float*)alloc((size_t)N * 4 * 4);
    float* el2   = (float*)alloc((size_t)N * 4);
    float* er2   = (float*)alloc((size_t)N * 4);
    int* icounts = (int*)alloc((size_t)N * 4);
    int* icursor = (int*)alloc((size_t)N * 4);
    int* ibsum   = (int*)alloc((size_t)(NB + 1) * 4);
    int* irowp   = (int*)alloc((size_t)(N + 1) * 4);
    int* icsrs   = (int*)alloc((size_t)E * 4);
    unsigned short* w1th = (unsigned short*)alloc((size_t)128 * 256 * 2);
    unsigned short* w1tl = (unsigned short*)alloc((size_t)128 * 256 * 2);
    unsigned short* hh   = (unsigned short*)alloc((size_t)N * 256 * 2);
    unsigned short* hl   = (unsigned short*)alloc((size_t)N * 256 * 2);
    unsigned short* w2th = (unsigned short*)alloc((size_t)256 * 64 * 2);
    unsigned short* w2tl = (unsigned short*)alloc((size_t)256 * 64 * 2);
    (void)ws_size;

    // --- CSR build (dst-indexed) ---
    // counts and cursor are adjacent allocations: zero them in one launch
    {
        int nz = (int)(((char*)icursor - (char*)icounts) / 4) + N;
        zero_kernel<<<128, 256, 0, stream>>>(icounts, nz);
    }
    hist_kernel<<<(E + 255) / 256, 256, 0, stream>>>(dst, icounts, E);
    bsum_kernel<<<NB, 256, 0, stream>>>(icounts, ibsum, N);
    bscan_kernel<<<1, 256, 0, stream>>>(ibsum, NB, irowp, N, E);
    rowptr_kernel<<<NB, 256, 0, stream>>>(icounts, ibsum, irowp, N);
    fill_kernel<<<(E + 255) / 256, 256, 0, stream>>>(src, dst, irowp, icursor, icsrs, E);

    // --- weight splits (both in one launch) ---
    splitT_both<<<(128 * 256 + 256 * 64 + 255) / 256, 256, 0, stream>>>(
        W1, w1th, w1tl, W2, w2th, w2tl);

    // --- layer 1 ---
    {
        dim3 g((N + 63) / 64, 256 / 64);
        gemm_mfma<true><<<g, 256, 0, stream>>>(x, nullptr, w1th, w1tl, feat1,
                                               al1, ar1, el1, er1, 4, N, 256, 128);
    }
    gat1_node<<<(N + 3) / 4, 256, 0, stream>>>(feat1, el1, er1, irowp, icsrs, b1, hh, hl, N);

    // --- layer 2 ---
    {
        dim3 g((N + 63) / 64, 1);
        gemm_mfma<false><<<g, 256, 0, stream>>>(hh, hl, w2th, w2tl, feat2,
                                                al2, ar2, el2, er2, 1, N, 64, 256);
    }
    gat2_node<<<(N + 3) / 4, 256, 0, stream>>>(feat2, el2, er2, irowp, icsrs, b2,
                                               (float*)d_out, (float*)d_out + N, N);
}

// Round 7
// 236.375 us; speedup vs baseline: 16.6003x; 1.0990x over previous
//
#include <hip/hip_runtime.h>
#include <hip/hip_bf16.h>

#define NEG_SLOPE 0.2f

typedef __attribute__((ext_vector_type(8))) short short8v;
typedef __attribute__((ext_vector_type(4))) float f32x4;

// ---------- bf16 round-to-nearest helpers ----------
__device__ __forceinline__ unsigned short f2bf(float f) {
    unsigned u = __float_as_uint(f);
    unsigned r = (u + 0x7FFFu + ((u >> 16) & 1u)) >> 16;
    return (unsigned short)r;
}
__device__ __forceinline__ float bf2f(unsigned short h) {
    return __uint_as_float((unsigned)h << 16);
}

// ---------- zero ints ----------
__global__ __launch_bounds__(256) void zero_kernel(int* p, int n) {
    int i = blockIdx.x * 256 + threadIdx.x;
    int stride = gridDim.x * 256;
    for (int k = i; k < n; k += stride) p[k] = 0;
}

// ---------- CSR build ----------
__global__ __launch_bounds__(256) void hist_kernel(const int* __restrict__ dst,
                                                   int* __restrict__ counts, int E) {
    int e = blockIdx.x * 256 + threadIdx.x;
    if (e < E) atomicAdd(counts + dst[e], 1);
}

__global__ __launch_bounds__(256) void bsum_kernel(const int* __restrict__ counts,
                                                   int* __restrict__ bsum, int N) {
    __shared__ int sh[256];
    int i = blockIdx.x * 256 + threadIdx.x;
    int v = (i < N) ? counts[i] : 0;
    sh[threadIdx.x] = v;
    __syncthreads();
    for (int off = 128; off > 0; off >>= 1) {
        if (threadIdx.x < off) sh[threadIdx.x] += sh[threadIdx.x + off];
        __syncthreads();
    }
    if (threadIdx.x == 0) bsum[blockIdx.x] = sh[0];
}

__global__ __launch_bounds__(256) void bscan_kernel(int* __restrict__ bsum, int nb,
                                                    int* __restrict__ rowptr, int N, int E) {
    __shared__ int sh[256];
    int tid = threadIdx.x;
    int carry = 0;
    for (int base = 0; base < nb; base += 256) {
        int i = base + tid;
        int v = (i < nb) ? bsum[i] : 0;
        sh[tid] = v;
        __syncthreads();
        for (int off = 1; off < 256; off <<= 1) {
            int t = (tid >= off) ? sh[tid - off] : 0;
            __syncthreads();
            sh[tid] += t;
            __syncthreads();
        }
        if (i < nb) bsum[i] = carry + sh[tid] - v;  // exclusive
        int tot = sh[255];
        __syncthreads();
        carry += tot;
    }
    if (tid == 0) rowptr[N] = E;
}

__global__ __launch_bounds__(256) void rowptr_kernel(const int* __restrict__ counts,
                                                     const int* __restrict__ bsum,
                                                     int* __restrict__ rowptr, int N) {
    __shared__ int sh[256];
    int i = blockIdx.x * 256 + threadIdx.x;
    int tid = threadIdx.x;
    int v = (i < N) ? counts[i] : 0;
    sh[tid] = v;
    __syncthreads();
    for (int off = 1; off < 256; off <<= 1) {
        int t = (tid >= off) ? sh[tid - off] : 0;
        __syncthreads();
        sh[tid] += t;
        __syncthreads();
    }
    if (i < N) rowptr[i] = bsum[blockIdx.x] + sh[tid] - v;  // exclusive
}

__global__ __launch_bounds__(256) void fill_kernel(const int* __restrict__ src,
                                                   const int* __restrict__ dst,
                                                   const int* __restrict__ rowptr,
                                                   int* __restrict__ cursor,
                                                   int* __restrict__ csr_src, int E) {
    int e = blockIdx.x * 256 + threadIdx.x;
    if (e >= E) return;
    int d = dst[e];
    int pos = atomicAdd(cursor + d, 1);
    csr_src[rowptr[d] + pos] = src[e];
}

// ---------- split + transpose BOTH weights in one launch ----------
// W1[128,256] -> w1t hi/lo [256,128]; W2[256,64] -> w2t hi/lo [64,256]
__global__ __launch_bounds__(256) void splitT_both(const float* __restrict__ W1,
                                                   unsigned short* __restrict__ h1,
                                                   unsigned short* __restrict__ l1,
                                                   const float* __restrict__ W2,
                                                   unsigned short* __restrict__ h2,
                                                   unsigned short* __restrict__ l2) {
    int tid = blockIdx.x * 256 + threadIdx.x;
    if (tid < 128 * 256) {
        int k = tid >> 8, n = tid & 255;
        float f = W1[tid];
        unsigned short h = f2bf(f);
        h1[n * 128 + k] = h;
        l1[n * 128 + k] = f2bf(f - bf2f(h));
    } else {
        int t = tid - 128 * 256;
        if (t < 256 * 64) {
            int k = t >> 6, n = t & 63;
            float f = W2[t];
            unsigned short h = f2bf(f);
            h2[n * 256 + k] = h;
            l2[n * 256 + k] = f2bf(f - bf2f(h));
        }
    }
}

// ---------- MFMA GEMM with fused el/er epilogue ----------
// C[M,Nn](bf16) = A[M,K](bf16) @ Wt[Nn,K]^T  via B hi/lo x2 MFMA.
// BM=64, BN=64, BK=128; 256 thr = 4 waves; wave w -> rows w*16..+15.
// A block's 64 cols == one head (blockIdx.y); epilogue computes
// el[r*H+head] = sum_c feat*attn_l, er likewise (fp32 acc precision).
template<bool A_FP32>
__global__ __launch_bounds__(256) void gemm_mfma(const void* __restrict__ A_any,
                                                 const unsigned short* __restrict__ Bh_g,
                                                 const unsigned short* __restrict__ Bl_g,
                                                 unsigned short* __restrict__ C,
                                                 const float* __restrict__ attn_l,
                                                 const float* __restrict__ attn_r,
                                                 float* __restrict__ el,
                                                 float* __restrict__ er,
                                                 int H, int M, int Nn, int K) {
    __shared__ unsigned short Ah[64][136], Bh[64][136], Bl[64][136];
    int tid = threadIdx.x;
    int row0 = blockIdx.x * 64;
    int col0 = blockIdx.y * 64;
    int wv = tid >> 6;
    int lane = tid & 63;
    int l15 = lane & 15;
    int kgrp = (lane >> 4) * 8;

    f32x4 acc[4] = {{0.f,0.f,0.f,0.f},{0.f,0.f,0.f,0.f},{0.f,0.f,0.f,0.f},{0.f,0.f,0.f,0.f}};

    for (int kc = 0; kc < K; kc += 128) {
        __syncthreads();
        #pragma unroll
        for (int p = 0; p < 4; p++) {
            int idx = (p * 256 + tid) * 8;
            int r = idx >> 7;          // /128
            int c = idx & 127;
            int gr = row0 + r;
            if (A_FP32) {
                const float* A = (const float*)A_any;
                float4 v0 = {0,0,0,0}, v1 = {0,0,0,0};
                if (gr < M) {
                    v0 = *(const float4*)(A + (size_t)gr * K + kc + c);
                    v1 = *(const float4*)(A + (size_t)gr * K + kc + c + 4);
                }
                ushort4 h0, h1;
                h0.x = f2bf(v0.x); h0.y = f2bf(v0.y);
                h0.z = f2bf(v0.z); h0.w = f2bf(v0.w);
                h1.x = f2bf(v1.x); h1.y = f2bf(v1.y);
                h1.z = f2bf(v1.z); h1.w = f2bf(v1.w);
                *(ushort4*)&Ah[r][c]     = h0;
                *(ushort4*)&Ah[r][c + 4] = h1;
            } else {
                const unsigned short* Ah_g = (const unsigned short*)A_any;
                uint4 vh = {0,0,0,0};
                if (gr < M) vh = *(const uint4*)(Ah_g + (size_t)gr * K + kc + c);
                *(uint4*)&Ah[r][c] = vh;
            }
            // B tile: rows are output cols (Wt layout [Nn][K])
            uint4 wh = *(const uint4*)(Bh_g + (size_t)(col0 + r) * K + kc + c);
            uint4 wl = *(const uint4*)(Bl_g + (size_t)(col0 + r) * K + kc + c);
            *(uint4*)&Bh[r][c] = wh;
            *(uint4*)&Bl[r][c] = wl;
        }
        __syncthreads();
        #pragma unroll
        for (int kk = 0; kk < 4; kk++) {
            int kc0 = kk * 32 + kgrp;
            short8v ah = *(short8v*)&Ah[wv * 16 + l15][kc0];
            #pragma unroll
            for (int c = 0; c < 4; c++) {
                short8v bh = *(short8v*)&Bh[c * 16 + l15][kc0];
                short8v bl = *(short8v*)&Bl[c * 16 + l15][kc0];
                acc[c] = __builtin_amdgcn_mfma_f32_16x16x32_bf16(ah, bh, acc[c], 0, 0, 0);
                acc[c] = __builtin_amdgcn_mfma_f32_16x16x32_bf16(ah, bl, acc[c], 0, 0, 0);
            }
        }
    }
    // C/D layout: col = lane&15, row = (lane>>4)*4 + j
    float elp[4] = {0.f, 0.f, 0.f, 0.f};
    float erp[4] = {0.f, 0.f, 0.f, 0.f};
    const float* alh = attn_l + blockIdx.y * 64;
    const float* arh = attn_r + blockIdx.y * 64;
    #pragma unroll
    for (int c = 0; c < 4; c++) {
        float av = alh[c * 16 + l15];
        float rv = arh[c * 16 + l15];
        #pragma unroll
        for (int j = 0; j < 4; j++) {
            int r = row0 + wv * 16 + (lane >> 4) * 4 + j;
            if (r < M) C[(size_t)r * Nn + col0 + c * 16 + l15] = f2bf(acc[c][j]);
            elp[j] += acc[c][j] * av;
            erp[j] += acc[c][j] * rv;
        }
    }
    #pragma unroll
    for (int j = 0; j < 4; j++) {
        #pragma unroll
        for (int off = 1; off < 16; off <<= 1) {
            elp[j] += __shfl_xor(elp[j], off);
            erp[j] += __shfl_xor(erp[j], off);
        }
    }
    if (l15 == 0) {
        #pragma unroll
        for (int j = 0; j < 4; j++) {
            int r = row0 + wv * 16 + (lane >> 4) * 4 + j;
            if (r < M) {
                el[(size_t)r * H + blockIdx.y] = elp[j];
                er[(size_t)r * H + blockIdx.y] = erp[j];
            }
        }
    }
}

// ---------- layer1 fused per-node, single-pass softmax, unroll x8 ----------
// one wave per node; bf16 feat gather; out = bf16 h only (GEMM2 A operand)
__global__ __launch_bounds__(256) void gat1_node(const unsigned short* __restrict__ feat,
                                                 const float* __restrict__ el,
                                                 const float* __restrict__ er,
                                                 const int* __restrict__ rowptr,
                                                 const int* __restrict__ csr_src,
                                                 const float* __restrict__ bias,
                                                 unsigned short* __restrict__ out_h, int N) {
    int node = (blockIdx.x * 256 + threadIdx.x) >> 6;
    int lane = threadIdx.x & 63;
    if (node >= N) return;
    int h = lane >> 4;
    int beg = rowptr[node], end = rowptr[node + 1];
    float erd = er[(size_t)node * 4 + h];
    float den = 0.f;
    float4 acc = {0.f, 0.f, 0.f, 0.f};
    int k = beg;
    for (; k + 7 < end; k += 8) {
        int s[8];
        #pragma unroll
        for (int u = 0; u < 8; u++) s[u] = csr_src[k + u];
        float e[8];
        #pragma unroll
        for (int u = 0; u < 8; u++) e[u] = el[(size_t)s[u] * 4 + h];
        ushort4 f[8];
        #pragma unroll
        for (int u = 0; u < 8; u++)
            f[u] = *(const ushort4*)(feat + (size_t)s[u] * 256 + lane * 4);
        #pragma unroll
        for (int u = 0; u < 8; u++) {
            float sc = e[u] + erd;
            sc = sc > 0.f ? sc : NEG_SLOPE * sc;
            float w = __expf(sc);
            den += w;
            acc.x += w * bf2f(f[u].x);
            acc.y += w * bf2f(f[u].y);
            acc.z += w * bf2f(f[u].z);
            acc.w += w * bf2f(f[u].w);
        }
    }
    for (; k + 3 < end; k += 4) {
        int s[4];
        #pragma unroll
        for (int u = 0; u < 4; u++) s[u] = csr_src[k + u];
        float e[4];
        #pragma unroll
        for (int u = 0; u < 4; u++) e[u] = el[(size_t)s[u] * 4 + h];
        ushort4 f[4];
        #pragma unroll
        for (int u = 0; u < 4; u++)
            f[u] = *(const ushort4*)(feat + (size_t)s[u] * 256 + lane * 4);
        #pragma unroll
        for (int u = 0; u < 4; u++) {
            float sc = e[u] + erd;
            sc = sc > 0.f ? sc : NEG_SLOPE * sc;
            float w = __expf(sc);
            den += w;
            acc.x += w * bf2f(f[u].x);
            acc.y += w * bf2f(f[u].y);
            acc.z += w * bf2f(f[u].z);
            acc.w += w * bf2f(f[u].w);
        }
    }
    for (; k < end; k++) {
        int s = csr_src[k];
        float sc = el[(size_t)s * 4 + h] + erd;
        sc = sc > 0.f ? sc : NEG_SLOPE * sc;
        float w = __expf(sc);
        ushort4 f = *(const ushort4*)(feat + (size_t)s * 256 + lane * 4);
        den += w;
        acc.x += w * bf2f(f.x);
        acc.y += w * bf2f(f.y);
        acc.z += w * bf2f(f.z);
        acc.w += w * bf2f(f.w);
    }
    float inv = (den > 0.f) ? 1.f / den : 0.f;
    float4 b = *(const float4*)(bias + lane * 4);
    ushort4 oh;
    oh.x = f2bf(fmaxf(acc.x * inv + b.x, 0.f));
    oh.y = f2bf(fmaxf(acc.y * inv + b.y, 0.f));
    oh.z = f2bf(fmaxf(acc.z * inv + b.z, 0.f));
    oh.w = f2bf(fmaxf(acc.w * inv + b.w, 0.f));
    *(ushort4*)(out_h + (size_t)node * 256 + lane * 4) = oh;
}

// ---------- layer2 fused per-node, single-pass + bias + relu + row-sum, unroll x8 ----------
__global__ __launch_bounds__(256) void gat2_node(const unsigned short* __restrict__ feat,
                                                 const float* __restrict__ el,
                                                 const float* __restrict__ er,
                                                 const int* __restrict__ rowptr,
                                                 const int* __restrict__ csr_src,
                                                 const float* __restrict__ bias,
                                                 float* __restrict__ emb,
                                                 float* __restrict__ go, int N) {
    int node = (blockIdx.x * 256 + threadIdx.x) >> 6;
    int lane = threadIdx.x & 63;
    if (node >= N) return;
    int beg = rowptr[node], end = rowptr[node + 1];
    float erd = er[node];
    float den = 0.f, acc = 0.f;
    int k = beg;
    for (; k + 7 < end; k += 8) {
        int s[8];
        #pragma unroll
        for (int u = 0; u < 8; u++) s[u] = csr_src[k + u];
        float e[8];
        #pragma unroll
        for (int u = 0; u < 8; u++) e[u] = el[s[u]];
        unsigned short f[8];
        #pragma unroll
        for (int u = 0; u < 8; u++) f[u] = feat[(size_t)s[u] * 64 + lane];
        #pragma unroll
        for (int u = 0; u < 8; u++) {
            float sc = e[u] + erd;
            sc = sc > 0.f ? sc : NEG_SLOPE * sc;
            float w = __expf(sc);
            den += w;
            acc += w * bf2f(f[u]);
        }
    }
    for (; k + 3 < end; k += 4) {
        int s[4];
        #pragma unroll
        for (int u = 0; u < 4; u++) s[u] = csr_src[k + u];
        float e[4];
        #pragma unroll
        for (int u = 0; u < 4; u++) e[u] = el[s[u]];
        unsigned short f[4];
        #pragma unroll
        for (int u = 0; u < 4; u++) f[u] = feat[(size_t)s[u] * 64 + lane];
        #pragma unroll
        for (int u = 0; u < 4; u++) {
            float sc = e[u] + erd;
            sc = sc > 0.f ? sc : NEG_SLOPE * sc;
            float w = __expf(sc);
            den += w;
            acc += w * bf2f(f[u]);
        }
    }
    for (; k < end; k++) {
        int s = csr_src[k];
        float sc = el[s] + erd;
        sc = sc > 0.f ? sc : NEG_SLOPE * sc;
        float w = __expf(sc);
        den += w;
        acc += w * bf2f(feat[(size_t)s * 64 + lane]);
    }
    float inv = (den > 0.f) ? 1.f / den : 0.f;
    float v = fmaxf(acc * inv + bias[lane], 0.f);
    go[(size_t)node * 64 + lane] = v;
    float sum = v;
    #pragma unroll
    for (int off = 1; off < 64; off <<= 1) sum += __shfl_xor(sum, off);
    if (lane == 0) emb[node] = sum;
}

extern "C" void kernel_launch(void* const* d_in, const int* in_sizes, int n_in,
                              void* d_out, int out_size, void* d_ws, size_t ws_size,
                              hipStream_t stream) {
    const float* x   = (const float*)d_in[0];
    const int*   src = (const int*)d_in[1];
    const int*   dst = (const int*)d_in[2];
    const float* W1  = (const float*)d_in[3];
    const float* al1 = (const float*)d_in[4];
    const float* ar1 = (const float*)d_in[5];
    const float* b1  = (const float*)d_in[6];
    const float* W2  = (const float*)d_in[7];
    const float* al2 = (const float*)d_in[8];
    const float* ar2 = (const float*)d_in[9];
    const float* b2  = (const float*)d_in[10];
    const int N = in_sizes[0] / 128;
    const int E = in_sizes[1];
    const int NB = (N + 255) / 256;

    char* base = (char*)d_ws;
    size_t off = 0;
    auto alloc = [&](size_t bytes) {
        off = (off + 255) & ~(size_t)255;
        void* p = base + off;
        off += bytes;
        return p;
    };
    unsigned short* feat1 = (unsigned short*)alloc((size_t)N * 256 * 2);
    unsigned short* feat2 = (unsigned short*)alloc((size_t)N * 64 * 2);
    float* el1   = (float*)alloc((size_t)N * 4 * 4);
    float* er1   = (float*)alloc((size_t)N * 4 * 4);
    float* el2   = (float*)alloc((size_t)N * 4);
    float* er2   = (float*)alloc((size_t)N * 4);
    int* icounts = (int*)alloc((size_t)N * 4);
    int* icursor = (int*)alloc((size_t)N * 4);
    int* ibsum   = (int*)alloc((size_t)(NB + 1) * 4);
    int* irowp   = (int*)alloc((size_t)(N + 1) * 4);
    int* icsrs   = (int*)alloc((size_t)E * 4);
    unsigned short* w1th = (unsigned short*)alloc((size_t)128 * 256 * 2);
    unsigned short* w1tl = (unsigned short*)alloc((size_t)128 * 256 * 2);
    unsigned short* hh   = (unsigned short*)alloc((size_t)N * 256 * 2);
    unsigned short* w2th = (unsigned short*)alloc((size_t)256 * 64 * 2);
    unsigned short* w2tl = (unsigned short*)alloc((size_t)256 * 64 * 2);
    (void)ws_size;

    // --- CSR build (dst-indexed) ---
    // counts and cursor are adjacent allocations: zero them in one launch
    {
        int nz = (int)(((char*)icursor - (char*)icounts) / 4) + N;
        zero_kernel<<<128, 256, 0, stream>>>(icounts, nz);
    }
    hist_kernel<<<(E + 255) / 256, 256, 0, stream>>>(dst, icounts, E);
    bsum_kernel<<<NB, 256, 0, stream>>>(icounts, ibsum, N);
    bscan_kernel<<<1, 256, 0, stream>>>(ibsum, NB, irowp, N, E);
    rowptr_kernel<<<NB, 256, 0, stream>>>(icounts, ibsum, irowp, N);
    fill_kernel<<<(E + 255) / 256, 256, 0, stream>>>(src, dst, irowp, icursor, icsrs, E);

    // --- weight splits (both in one launch) ---
    splitT_both<<<(128 * 256 + 256 * 64 + 255) / 256, 256, 0, stream>>>(
        W1, w1th, w1tl, W2, w2th, w2tl);

    // --- layer 1 ---
    {
        dim3 g((N + 63) / 64, 256 / 64);
        gemm_mfma<true><<<g, 256, 0, stream>>>(x, w1th, w1tl, feat1,
                                               al1, ar1, el1, er1, 4, N, 256, 128);
    }
    gat1_node<<<(N + 3) / 4, 256, 0, stream>>>(feat1, el1, er1, irowp, icsrs, b1, hh, N);

    // --- layer 2 ---
    {
        dim3 g((N + 63) / 64, 1);
        gemm_mfma<false><<<g, 256, 0, stream>>>(hh, w2th, w2tl, feat2,
                                                al2, ar2, el2, er2, 1, N, 64, 256);
    }
    gat2_node<<<(N + 3) / 4, 256, 0, stream>>>(feat2, el2, er2, irowp, icsrs, b2,
                                               (float*)d_out, (float*)d_out + N, N);
}